// Round 2
// baseline (1376.099 us; speedup 1.0000x reference)
//
#include <hip/hip_runtime.h>
#include <math.h>

typedef float f32x4 __attribute__((ext_vector_type(4)));
typedef __bf16 bf16x8 __attribute__((ext_vector_type(8)));
typedef __bf16 bf16x4 __attribute__((ext_vector_type(4)));

// Problem constants
static constexpr int NB = 2, NT = 2048, NC = 1024, NH = 16, ND = 64;
static constexpr int NM = NB * NT;   // 4096 rows

// ---------------------------------------------------------------------------
// fp32 -> bf16 convert (vectorized x4)
__global__ __launch_bounds__(256) void k_convert(const float* __restrict__ src,
                                                 __bf16* __restrict__ dst, int n4) {
  int i = blockIdx.x * 256 + threadIdx.x;
  if (i >= n4) return;
  float4 v = ((const float4*)src)[i];
  bf16x4 o;
  o.x = (__bf16)v.x; o.y = (__bf16)v.y; o.z = (__bf16)v.z; o.w = (__bf16)v.w;
  ((bf16x4*)dst)[i] = o;
}

// ---------------------------------------------------------------------------
// 1024x1024 fp32 [k][n] -> bf16 [n][k] transpose (LDS-tiled, coalesced)
__global__ __launch_bounds__(256) void k_transpose(const float* __restrict__ src,
                                                   __bf16* __restrict__ dst) {
  __shared__ float t[64][65];
  int r0 = blockIdx.y * 64, c0 = blockIdx.x * 64;
  int lr = threadIdx.x >> 6;   // 0..3
  int lc = threadIdx.x & 63;
#pragma unroll
  for (int j = 0; j < 16; j++) {
    int r = j * 4 + lr;
    t[r][lc] = src[(size_t)(r0 + r) * 1024 + c0 + lc];
  }
  __syncthreads();
#pragma unroll
  for (int j = 0; j < 16; j++) {
    int r = j * 4 + lr;
    dst[(size_t)(c0 + r) * 1024 + r0 + lc] = (__bf16)t[lc][r];
  }
}

// ---------------------------------------------------------------------------
// bf16 MFMA GEMM: C[M,1024] = A[M,1024] @ B^T (B stored [n][k] bf16), fp32 out
// 128x128 tile, BK=32, 4 waves (2x2 of 64x64), reg-staged LDS.
// Up to 4 (B,C) pairs fused along grid.y (sel = blockIdx.y / nblkPer).
__global__ __launch_bounds__(256) void k_gemm(const __bf16* __restrict__ A,
    const __bf16* B0, const __bf16* B1, const __bf16* B2, const __bf16* B3,
    float* C0, float* C1, float* C2, float* C3, int nblkPer) {
  constexpr int Kd = 1024;
  int mblk = blockIdx.x;
  int yb = blockIdx.y;
  int sel = yb / nblkPer;
  int nb = yb % nblkPer;
  const __bf16* Bt = sel == 0 ? B0 : sel == 1 ? B1 : sel == 2 ? B2 : B3;
  float* Cp = sel == 0 ? C0 : sel == 1 ? C1 : sel == 2 ? C2 : C3;

  __shared__ __bf16 As[128 * 32];
  __shared__ __bf16 Bs[128 * 32];
  int tid = threadIdx.x;
  int lane = tid & 63;
  int w = tid >> 6;
  int wr = w >> 1, wc = w & 1;

  f32x4 acc[4][4];
#pragma unroll
  for (int r = 0; r < 4; r++)
#pragma unroll
    for (int c = 0; c < 4; c++) acc[r][c] = (f32x4){0.f, 0.f, 0.f, 0.f};

  int rowh = tid >> 2;          // 0..63
  int kcol = (tid & 3) * 8;
  const __bf16* aS = A + (size_t)(mblk * 128 + rowh) * Kd + kcol;
  const __bf16* bS = Bt + (size_t)(nb * 128 + rowh) * Kd + kcol;
  // fragment LDS addresses: row/col = lane&15 (+16*frag), k = (lane>>4)*8
  int rbase = (wr * 64 + (lane & 15)) * 32 + ((lane >> 4) * 8);
  int cbase = (wc * 64 + (lane & 15)) * 32 + ((lane >> 4) * 8);

  for (int kt = 0; kt < Kd; kt += 32) {
    uint4 a0 = *(const uint4*)(aS + kt);
    uint4 a1 = *(const uint4*)(aS + (size_t)64 * Kd + kt);
    uint4 b0 = *(const uint4*)(bS + kt);
    uint4 b1 = *(const uint4*)(bS + (size_t)64 * Kd + kt);
    __syncthreads();
    *(uint4*)&As[rowh * 32 + kcol] = a0;
    *(uint4*)&As[(rowh + 64) * 32 + kcol] = a1;
    *(uint4*)&Bs[rowh * 32 + kcol] = b0;
    *(uint4*)&Bs[(rowh + 64) * 32 + kcol] = b1;
    __syncthreads();
    bf16x8 af[4], bfr[4];
#pragma unroll
    for (int r = 0; r < 4; r++) af[r] = *(const bf16x8*)&As[rbase + r * 16 * 32];
#pragma unroll
    for (int c = 0; c < 4; c++) bfr[c] = *(const bf16x8*)&Bs[cbase + c * 16 * 32];
#pragma unroll
    for (int r = 0; r < 4; r++)
#pragma unroll
      for (int c = 0; c < 4; c++)
        acc[r][c] = __builtin_amdgcn_mfma_f32_16x16x32_bf16(af[r], bfr[c], acc[r][c], 0, 0, 0);
  }
  // C/D layout: col = lane&15, row = (lane>>4)*4 + j   [verified m89]
  int orow = mblk * 128 + wr * 64 + ((lane >> 4) << 2);
  int ocol = nb * 128 + wc * 64 + (lane & 15);
#pragma unroll
  for (int r = 0; r < 4; r++)
#pragma unroll
    for (int c = 0; c < 4; c++)
#pragma unroll
      for (int j = 0; j < 4; j++)
        Cp[(size_t)(orow + r * 16 + j) * 1024 + ocol + c * 16] = acc[r][c][j];
}

// ---------------------------------------------------------------------------
// small projections: gk = -exp(A_log)*softplus(x@Wgk + dt_bias),
//                    beta = sigmoid(x@Wb + bb). Layout out: [b*16+h][t]
__global__ __launch_bounds__(256) void k_projsmall(const float* __restrict__ x,
    const float* __restrict__ Wgk, const float* __restrict__ Wb,
    const float* __restrict__ bb, const float* __restrict__ A_log,
    const float* __restrict__ dtb, float* __restrict__ gk_arr,
    float* __restrict__ beta_arr) {
  int m = blockIdx.x;
  int b = m >> 11, t = m & 2047;
  int tid = threadIdx.x;
  int j = tid >> 3;   // 0..31 (16 gk + 16 beta)
  int p = tid & 7;
  const float* xr = x + (size_t)m * 1024;
  const float* Wcol;
  int jj;
  if (j < 16) { Wcol = Wgk; jj = j; } else { Wcol = Wb; jj = j - 16; }
  float s = 0.f;
  for (int i = p; i < 1024; i += 8) s += xr[i] * Wcol[i * 16 + jj];
  s += __shfl_xor(s, 1);
  s += __shfl_xor(s, 2);
  s += __shfl_xor(s, 4);
  if (p == 0) {
    if (j < 16) {
      float v = s + dtb[jj];
      float sp = v > 20.f ? v : log1pf(__expf(v));
      gk_arr[((size_t)(b * 16 + jj)) * 2048 + t] = -__expf(A_log[jj]) * sp;
    } else {
      float v = s + bb[jj];
      beta_arr[((size_t)(b * 16 + jj)) * 2048 + t] = 1.f / (1.f + __expf(-v));
    }
  }
}

// ---------------------------------------------------------------------------
// depthwise causal conv(K=4) + silu; for q,k additionally l2norm + rope(32).
// grid (T/64, B*H, 3): z=0 q, z=1 k, z=2 v. Output layout [b*16+h][t][64].
__global__ __launch_bounds__(256) void k_conv(
    const float* __restrict__ qpre, const float* __restrict__ kpre,
    const float* __restrict__ vpre, const float* __restrict__ cqw,
    const float* __restrict__ ckw, const float* __restrict__ cvw,
    float* __restrict__ qhat, float* __restrict__ khat, float* __restrict__ vhat) {
  int z = blockIdx.z;
  const float* src = z == 0 ? qpre : z == 1 ? kpre : vpre;
  const float* cw = z == 0 ? cqw : z == 1 ? ckw : cvw;
  float* dst = z == 0 ? qhat : z == 1 ? khat : vhat;
  int t0 = blockIdx.x * 64;
  int bh = blockIdx.y;
  int b = bh >> 4, h = bh & 15;
  int tid = threadIdx.x;
  __shared__ float tile[67 * 64];
  __shared__ float outb[64 * 64];
  for (int i = tid; i < 67 * 64; i += 256) {
    int r = i >> 6, c = i & 63;
    int t = t0 - 3 + r;
    tile[i] = (t >= 0) ? src[((size_t)(b * 2048 + t)) * 1024 + h * 64 + c] : 0.f;
  }
  __syncthreads();
  int c = tid & 63;
  int rb = (tid >> 6) * 16;
  float4 w4 = *(const float4*)&cw[(h * 64 + c) * 4];
  size_t obase = ((size_t)bh) * 2048 * 64;
#pragma unroll
  for (int rr = 0; rr < 16; rr++) {
    int r = rb + rr;
    float y = tile[r * 64 + c] * w4.x + tile[(r + 1) * 64 + c] * w4.y +
              tile[(r + 2) * 64 + c] * w4.z + tile[(r + 3) * 64 + c] * w4.w;
    float sv = y * (1.f / (1.f + __expf(-y)));
    if (z == 2) dst[obase + (size_t)(t0 + r) * 64 + c] = sv;
    else outb[r * 64 + c] = sv;
  }
  if (z == 2) return;
  __syncthreads();
  int r = tid >> 2;
  int p = tid & 3;
  float ss = 0.f;
#pragma unroll
  for (int i2 = 0; i2 < 16; i2++) { float vv = outb[r * 64 + p * 16 + i2]; ss += vv * vv; }
  ss += __shfl_xor(ss, 1);
  ss += __shfl_xor(ss, 2);
  float inv = rsqrtf(ss + 1e-6f);   // l2norm: sum (not mean), eps 1e-6
  int tg = t0 + r;
#pragma unroll
  for (int i2 = 0; i2 < 16; i2++) {
    int cc = p * 16 + i2;
    float val = outb[r * 64 + cc] * inv;
    float res;
    if (cc < 16) {
      float x2 = outb[r * 64 + cc + 16] * inv;
      float ang = tg * __expf(-0.5756462732485114f * cc);   // ln(1e4)/16
      float sn, cn; sincosf(ang, &sn, &cn);
      res = val * cn - x2 * sn;
    } else if (cc < 32) {
      float x1 = outb[r * 64 + cc - 16] * inv;
      float ang = tg * __expf(-0.5756462732485114f * (cc - 16));
      float sn, cn; sincosf(ang, &sn, &cn);
      res = val * cn + x1 * sn;
    } else res = val;
    dst[obase + (size_t)tg * 64 + cc] = res;
  }
}

// ---------------------------------------------------------------------------
// sequential gated delta scan. grid 64 = (b*16+h)*2 + vhalf.
// 256 threads own S[64][32]: thread (kb=tid>>5 owns k-rows kb*8..+7, col v=tid&31).
__global__ __launch_bounds__(256) void k_scan(const float* __restrict__ qhat,
    const float* __restrict__ khat, const float* __restrict__ vhat,
    const float* __restrict__ gk_arr, const float* __restrict__ beta_arr,
    float* __restrict__ o_pre) {
  int bid = blockIdx.x;
  int bh = bid >> 1, vh = bid & 1;
  int b = bh >> 4, h = bh & 15;
  int tid = threadIdx.x;
  int v = tid & 31, kb = tid >> 5;
  __shared__ float ks[32 * 64], qs[32 * 64], vs[32 * 32];
  __shared__ float egs[32], bts[32];
  __shared__ float predbuf[256], obuf[256];
  float S[8];
#pragma unroll
  for (int r = 0; r < 8; r++) S[r] = 0.f;
  size_t base = (size_t)bh * (2048 * 64);
  size_t gbase = (size_t)bh * 2048;
  for (int ch = 0; ch < 64; ch++) {
    int t0 = ch * 32;
    __syncthreads();
    for (int i = tid; i < 2048; i += 256) {
      ks[i] = khat[base + (size_t)t0 * 64 + i];
      qs[i] = qhat[base + (size_t)t0 * 64 + i];
    }
    for (int i = tid; i < 1024; i += 256) {
      int rr = i >> 5, cc2 = i & 31;
      vs[i] = vhat[base + (size_t)(t0 + rr) * 64 + vh * 32 + cc2];
    }
    if (tid < 32) {
      egs[tid] = __expf(gk_arr[gbase + t0 + tid]);
      bts[tid] = beta_arr[gbase + t0 + tid];
    }
    __syncthreads();
    for (int i = 0; i < 32; i++) {
      float kk[8];
#pragma unroll
      for (int r = 0; r < 8; r++) kk[r] = ks[i * 64 + kb * 8 + r];
      float part = 0.f;
#pragma unroll
      for (int r = 0; r < 8; r++) part += kk[r] * S[r];
      predbuf[tid] = part;
      __syncthreads();
      float pred = 0.f;
#pragma unroll
      for (int jj = 0; jj < 8; jj++) pred += predbuf[jj * 32 + v];
      float eg = egs[i], bt = bts[i], vv = vs[i * 32 + v];
      float delta = bt * (vv - eg * pred);   // pred on gated state = eg * (k.S_old)
      float op = 0.f;
#pragma unroll
      for (int r = 0; r < 8; r++) S[r] = eg * S[r] + kk[r] * delta;
#pragma unroll
      for (int r = 0; r < 8; r++) op += qs[i * 64 + kb * 8 + r] * S[r];
      obuf[tid] = op;
      __syncthreads();
      if (tid < 32) {
        float o = 0.f;
#pragma unroll
        for (int jj = 0; jj < 8; jj++) o += obuf[jj * 32 + tid];
        o_pre[((size_t)(b * 2048 + t0 + i)) * 1024 + h * 64 + vh * 32 + tid] = o;
      }
    }
  }
}

// ---------------------------------------------------------------------------
// epilogue: per-(m,h) RMSNorm(64, eps 1e-5, mean) * gnorm_w * silu(g) -> bf16
__global__ __launch_bounds__(256) void k_gatenorm(const float* __restrict__ o_pre,
    const float* __restrict__ g, const float* __restrict__ gnw,
    __bf16* __restrict__ obf) {
  int m = blockIdx.x;
  int tid = threadIdx.x;
  size_t baseo = (size_t)m * 1024 + tid * 4;
  float4 ov = *(const float4*)&o_pre[baseo];
  float ss = ov.x * ov.x + ov.y * ov.y + ov.z * ov.z + ov.w * ov.w;
  ss += __shfl_xor(ss, 1);
  ss += __shfl_xor(ss, 2);
  ss += __shfl_xor(ss, 4);
  ss += __shfl_xor(ss, 8);
  float inv = rsqrtf(ss * (1.f / 64.f) + 1e-5f);
  float4 gv = *(const float4*)&g[baseo];
  int d0 = (tid & 15) * 4;
  float r0 = ov.x * inv * gnw[d0 + 0] * (gv.x * (1.f / (1.f + __expf(-gv.x))));
  float r1 = ov.y * inv * gnw[d0 + 1] * (gv.y * (1.f / (1.f + __expf(-gv.y))));
  float r2 = ov.z * inv * gnw[d0 + 2] * (gv.z * (1.f / (1.f + __expf(-gv.z))));
  float r3 = ov.w * inv * gnw[d0 + 3] * (gv.w * (1.f / (1.f + __expf(-gv.w))));
  bf16x4 o;
  o.x = (__bf16)r0; o.y = (__bf16)r1; o.z = (__bf16)r2; o.w = (__bf16)r3;
  *(bf16x4*)&obf[baseo] = o;
}

// ---------------------------------------------------------------------------
extern "C" void kernel_launch(void* const* d_in, const int* in_sizes, int n_in,
                              void* d_out, int out_size, void* d_ws, size_t ws_size,
                              hipStream_t stream) {
  const float* x = (const float*)d_in[0];
  const float* Wq = (const float*)d_in[1];
  const float* Wk = (const float*)d_in[2];
  const float* Wv = (const float*)d_in[3];
  const float* Wo = (const float*)d_in[4];
  const float* Wg = (const float*)d_in[5];
  const float* Wgk = (const float*)d_in[6];
  const float* Wb = (const float*)d_in[7];
  const float* bb = (const float*)d_in[8];
  const float* A_log = (const float*)d_in[9];
  const float* cqw = (const float*)d_in[10];
  const float* ckw = (const float*)d_in[11];
  const float* cvw = (const float*)d_in[12];
  const float* gnw = (const float*)d_in[13];
  const float* dtb = (const float*)d_in[14];
  float* out = (float*)d_out;

  char* ws = (char*)d_ws;
  // workspace layout (bytes)
  __bf16* xbf   = (__bf16*)(ws + 0);            // 8 MB   (reused as obf later)
  __bf16* wq_t  = (__bf16*)(ws + 8388608);      // 2 MB
  __bf16* wk_t  = (__bf16*)(ws + 10485760);
  __bf16* wv_t  = (__bf16*)(ws + 12582912);
  __bf16* wg_t  = (__bf16*)(ws + 14680064);
  __bf16* wo_t  = (__bf16*)(ws + 16777216);
  float* qpre   = (float*)(ws + 18874368);      // 16 MB  (reused as o_pre later)
  float* kpre   = (float*)(ws + 35651584);
  float* vpre   = (float*)(ws + 52428800);
  float* gbuf   = (float*)(ws + 69206016);
  float* qhat   = (float*)(ws + 85983232);
  float* khat   = (float*)(ws + 102760448);
  float* vhat   = (float*)(ws + 119537664);
  float* gk_arr = (float*)(ws + 136314880);     // 256 KB
  float* beta_a = (float*)(ws + 136577024);     // 256 KB
  float* o_pre  = qpre;     // qpre dead after k_conv
  __bf16* obf   = xbf;      // xbf dead after first gemm

  // 1. convert x to bf16
  k_convert<<<dim3((NM * NC / 4 + 255) / 256), 256, 0, stream>>>(x, xbf, NM * NC / 4);
  // 2. transpose weights to [n][k] bf16
  dim3 tg(16, 16);
  k_transpose<<<tg, 256, 0, stream>>>(Wq, wq_t);
  k_transpose<<<tg, 256, 0, stream>>>(Wk, wk_t);
  k_transpose<<<tg, 256, 0, stream>>>(Wv, wv_t);
  k_transpose<<<tg, 256, 0, stream>>>(Wg, wg_t);
  k_transpose<<<tg, 256, 0, stream>>>(Wo, wo_t);
  // 3. fused q/k/v/g projections
  k_gemm<<<dim3(NM / 128, 32), 256, 0, stream>>>(xbf, wq_t, wk_t, wv_t, wg_t,
                                                 qpre, kpre, vpre, gbuf, 8);
  // 4. gk / beta small projections
  k_projsmall<<<NM, 256, 0, stream>>>(x, Wgk, Wb, bb, A_log, dtb, gk_arr, beta_a);
  // 5. conv + silu (+ l2norm + rope for q,k)
  k_conv<<<dim3(NT / 64, NB * NH, 3), 256, 0, stream>>>(qpre, kpre, vpre, cqw, ckw,
                                                        cvw, qhat, khat, vhat);
  // 6. sequential gated delta scan
  k_scan<<<64, 256, 0, stream>>>(qhat, khat, vhat, gk_arr, beta_a, o_pre);
  // 7. rmsnorm + gate -> bf16
  k_gatenorm<<<NM, 256, 0, stream>>>(o_pre, gbuf, gnw, obf);
  // 8. output projection
  k_gemm<<<dim3(NM / 128, 8), 256, 0, stream>>>(obf, wo_t, nullptr, nullptr, nullptr,
                                                out, nullptr, nullptr, nullptr, 8);
}

// Round 3
// 848.980 us; speedup vs baseline: 1.6209x; 1.6209x over previous
//
#include <hip/hip_runtime.h>
#include <math.h>

typedef float f32x4 __attribute__((ext_vector_type(4)));
typedef __bf16 bf16x8 __attribute__((ext_vector_type(8)));
typedef __bf16 bf16x4 __attribute__((ext_vector_type(4)));

// Problem constants
static constexpr int NB = 2, NT = 2048, NC = 1024, NH = 16, ND = 64;
static constexpr int NM = NB * NT;   // 4096 rows

// ---------------------------------------------------------------------------
// fp32 -> bf16 convert (vectorized x4)
__global__ __launch_bounds__(256) void k_convert(const float* __restrict__ src,
                                                 __bf16* __restrict__ dst, int n4) {
  int i = blockIdx.x * 256 + threadIdx.x;
  if (i >= n4) return;
  float4 v = ((const float4*)src)[i];
  bf16x4 o;
  o.x = (__bf16)v.x; o.y = (__bf16)v.y; o.z = (__bf16)v.z; o.w = (__bf16)v.w;
  ((bf16x4*)dst)[i] = o;
}

// ---------------------------------------------------------------------------
// 1024x1024 fp32 [k][n] -> bf16 [n][k] transpose (LDS-tiled, coalesced)
__global__ __launch_bounds__(256) void k_transpose(const float* __restrict__ src,
                                                   __bf16* __restrict__ dst) {
  __shared__ float t[64][65];
  int r0 = blockIdx.y * 64, c0 = blockIdx.x * 64;
  int lr = threadIdx.x >> 6;   // 0..3
  int lc = threadIdx.x & 63;
#pragma unroll
  for (int j = 0; j < 16; j++) {
    int r = j * 4 + lr;
    t[r][lc] = src[(size_t)(r0 + r) * 1024 + c0 + lc];
  }
  __syncthreads();
#pragma unroll
  for (int j = 0; j < 16; j++) {
    int r = j * 4 + lr;
    dst[(size_t)(c0 + r) * 1024 + r0 + lc] = (__bf16)t[lc][r];
  }
}

// ---------------------------------------------------------------------------
// bf16 MFMA GEMM: C[M,1024] = A[M,1024] @ B^T (B stored [n][k] bf16), fp32 out
__global__ __launch_bounds__(256) void k_gemm(const __bf16* __restrict__ A,
    const __bf16* B0, const __bf16* B1, const __bf16* B2, const __bf16* B3,
    float* C0, float* C1, float* C2, float* C3, int nblkPer) {
  constexpr int Kd = 1024;
  int mblk = blockIdx.x;
  int yb = blockIdx.y;
  int sel = yb / nblkPer;
  int nb = yb % nblkPer;
  const __bf16* Bt = sel == 0 ? B0 : sel == 1 ? B1 : sel == 2 ? B2 : B3;
  float* Cp = sel == 0 ? C0 : sel == 1 ? C1 : sel == 2 ? C2 : C3;

  __shared__ __bf16 As[128 * 32];
  __shared__ __bf16 Bs[128 * 32];
  int tid = threadIdx.x;
  int lane = tid & 63;
  int w = tid >> 6;
  int wr = w >> 1, wc = w & 1;

  f32x4 acc[4][4];
#pragma unroll
  for (int r = 0; r < 4; r++)
#pragma unroll
    for (int c = 0; c < 4; c++) acc[r][c] = (f32x4){0.f, 0.f, 0.f, 0.f};

  int rowh = tid >> 2;          // 0..63
  int kcol = (tid & 3) * 8;
  const __bf16* aS = A + (size_t)(mblk * 128 + rowh) * Kd + kcol;
  const __bf16* bS = Bt + (size_t)(nb * 128 + rowh) * Kd + kcol;
  int rbase = (wr * 64 + (lane & 15)) * 32 + ((lane >> 4) * 8);
  int cbase = (wc * 64 + (lane & 15)) * 32 + ((lane >> 4) * 8);

  for (int kt = 0; kt < Kd; kt += 32) {
    uint4 a0 = *(const uint4*)(aS + kt);
    uint4 a1 = *(const uint4*)(aS + (size_t)64 * Kd + kt);
    uint4 b0 = *(const uint4*)(bS + kt);
    uint4 b1 = *(const uint4*)(bS + (size_t)64 * Kd + kt);
    __syncthreads();
    *(uint4*)&As[rowh * 32 + kcol] = a0;
    *(uint4*)&As[(rowh + 64) * 32 + kcol] = a1;
    *(uint4*)&Bs[rowh * 32 + kcol] = b0;
    *(uint4*)&Bs[(rowh + 64) * 32 + kcol] = b1;
    __syncthreads();
    bf16x8 af[4], bfr[4];
#pragma unroll
    for (int r = 0; r < 4; r++) af[r] = *(const bf16x8*)&As[rbase + r * 16 * 32];
#pragma unroll
    for (int c = 0; c < 4; c++) bfr[c] = *(const bf16x8*)&Bs[cbase + c * 16 * 32];
#pragma unroll
    for (int r = 0; r < 4; r++)
#pragma unroll
      for (int c = 0; c < 4; c++)
        acc[r][c] = __builtin_amdgcn_mfma_f32_16x16x32_bf16(af[r], bfr[c], acc[r][c], 0, 0, 0);
  }
  int orow = mblk * 128 + wr * 64 + ((lane >> 4) << 2);
  int ocol = nb * 128 + wc * 64 + (lane & 15);
#pragma unroll
  for (int r = 0; r < 4; r++)
#pragma unroll
    for (int c = 0; c < 4; c++)
#pragma unroll
      for (int j = 0; j < 4; j++)
        Cp[(size_t)(orow + r * 16 + j) * 1024 + ocol + c * 16] = acc[r][c][j];
}

// ---------------------------------------------------------------------------
// small projections: gk = -exp(A_log)*softplus(x@Wgk + dt_bias),
//                    beta = sigmoid(x@Wb + bb). Layout out: [b*16+h][t]
__global__ __launch_bounds__(256) void k_projsmall(const float* __restrict__ x,
    const float* __restrict__ Wgk, const float* __restrict__ Wb,
    const float* __restrict__ bb, const float* __restrict__ A_log,
    const float* __restrict__ dtb, float* __restrict__ gk_arr,
    float* __restrict__ beta_arr) {
  int m = blockIdx.x;
  int b = m >> 11, t = m & 2047;
  int tid = threadIdx.x;
  int j = tid >> 3;   // 0..31 (16 gk + 16 beta)
  int p = tid & 7;
  const float* xr = x + (size_t)m * 1024;
  const float* Wcol;
  int jj;
  if (j < 16) { Wcol = Wgk; jj = j; } else { Wcol = Wb; jj = j - 16; }
  float s = 0.f;
  for (int i = p; i < 1024; i += 8) s += xr[i] * Wcol[i * 16 + jj];
  s += __shfl_xor(s, 1);
  s += __shfl_xor(s, 2);
  s += __shfl_xor(s, 4);
  if (p == 0) {
    if (j < 16) {
      float v = s + dtb[jj];
      float sp = v > 20.f ? v : log1pf(__expf(v));
      gk_arr[((size_t)(b * 16 + jj)) * 2048 + t] = -__expf(A_log[jj]) * sp;
    } else {
      float v = s + bb[jj];
      beta_arr[((size_t)(b * 16 + jj)) * 2048 + t] = 1.f / (1.f + __expf(-v));
    }
  }
}

// ---------------------------------------------------------------------------
// depthwise causal conv(K=4) + silu; for q,k additionally l2norm + rope(32).
__global__ __launch_bounds__(256) void k_conv(
    const float* __restrict__ qpre, const float* __restrict__ kpre,
    const float* __restrict__ vpre, const float* __restrict__ cqw,
    const float* __restrict__ ckw, const float* __restrict__ cvw,
    float* __restrict__ qhat, float* __restrict__ khat, float* __restrict__ vhat) {
  int z = blockIdx.z;
  const float* src = z == 0 ? qpre : z == 1 ? kpre : vpre;
  const float* cw = z == 0 ? cqw : z == 1 ? ckw : cvw;
  float* dst = z == 0 ? qhat : z == 1 ? khat : vhat;
  int t0 = blockIdx.x * 64;
  int bh = blockIdx.y;
  int b = bh >> 4, h = bh & 15;
  int tid = threadIdx.x;
  __shared__ float tile[67 * 64];
  __shared__ float outb[64 * 64];
  for (int i = tid; i < 67 * 64; i += 256) {
    int r = i >> 6, c = i & 63;
    int t = t0 - 3 + r;
    tile[i] = (t >= 0) ? src[((size_t)(b * 2048 + t)) * 1024 + h * 64 + c] : 0.f;
  }
  __syncthreads();
  int c = tid & 63;
  int rb = (tid >> 6) * 16;
  float4 w4 = *(const float4*)&cw[(h * 64 + c) * 4];
  size_t obase = ((size_t)bh) * 2048 * 64;
#pragma unroll
  for (int rr = 0; rr < 16; rr++) {
    int r = rb + rr;
    float y = tile[r * 64 + c] * w4.x + tile[(r + 1) * 64 + c] * w4.y +
              tile[(r + 2) * 64 + c] * w4.z + tile[(r + 3) * 64 + c] * w4.w;
    float sv = y * (1.f / (1.f + __expf(-y)));
    if (z == 2) dst[obase + (size_t)(t0 + r) * 64 + c] = sv;
    else outb[r * 64 + c] = sv;
  }
  if (z == 2) return;
  __syncthreads();
  int r = tid >> 2;
  int p = tid & 3;
  float ss = 0.f;
#pragma unroll
  for (int i2 = 0; i2 < 16; i2++) { float vv = outb[r * 64 + p * 16 + i2]; ss += vv * vv; }
  ss += __shfl_xor(ss, 1);
  ss += __shfl_xor(ss, 2);
  float inv = rsqrtf(ss + 1e-6f);
  int tg = t0 + r;
#pragma unroll
  for (int i2 = 0; i2 < 16; i2++) {
    int cc = p * 16 + i2;
    float val = outb[r * 64 + cc] * inv;
    float res;
    if (cc < 16) {
      float x2 = outb[r * 64 + cc + 16] * inv;
      float ang = tg * __expf(-0.5756462732485114f * cc);   // ln(1e4)/16
      float sn, cn; sincosf(ang, &sn, &cn);
      res = val * cn - x2 * sn;
    } else if (cc < 32) {
      float x1 = outb[r * 64 + cc - 16] * inv;
      float ang = tg * __expf(-0.5756462732485114f * (cc - 16));
      float sn, cn; sincosf(ang, &sn, &cn);
      res = val * cn + x1 * sn;
    } else res = val;
    dst[obase + (size_t)tg * 64 + cc] = res;
  }
}

// ---------------------------------------------------------------------------
// Chunked gated-delta. Chunk L=64, NCH=32 chunks per bh, 32 bh.
// Phase A (parallel, 1024 blocks = bh*32+ch):
//   cum_t = inclusive cumsum(g); M[t][s] = b_t exp(cum_t-cum_s) (k_t.k_s), s<t
//   Solve (I+M)[U|W] = [diag(b)V | diag(b*Gamma)K]  (forward substitution)
__global__ __launch_bounds__(256) void k_chunkA(
    const float* __restrict__ khat, const float* __restrict__ vhat,
    const float* __restrict__ gk_arr, const float* __restrict__ beta_arr,
    float* __restrict__ cumbuf, float* __restrict__ Ubuf, float* __restrict__ Wbuf) {
  int bid = blockIdx.x;
  int bh = bid >> 5, ch = bid & 31;
  int tid = threadIdx.x;
  __shared__ float Ksh[64][65];
  __shared__ float Msh[64][65];
  __shared__ float UW[64][130];
  __shared__ float cumsh[64], bsh[64], Gsh[64];
  size_t kbase = (size_t)bh * (2048 * 64) + (size_t)ch * 4096;
  size_t gb = (size_t)bh * 2048 + ch * 64;
  if (tid < 64) {
    cumsh[tid] = gk_arr[gb + tid];   // temporarily raw g
    bsh[tid] = beta_arr[gb + tid];
  }
  for (int idx = tid; idx < 4096; idx += 256) {
    Ksh[idx >> 6][idx & 63] = khat[kbase + idx];
  }
  __syncthreads();
  if (tid == 0) {
    float a = 0.f;
    for (int t = 0; t < 64; t++) { a += cumsh[t]; cumsh[t] = a; }
  }
  __syncthreads();
  if (tid < 64) {
    Gsh[tid] = __expf(cumsh[tid]);
    cumbuf[(size_t)(bh * 32 + ch) * 64 + tid] = cumsh[tid];
  }
  // M (strictly lower)
  {
    int t = tid >> 2, s0 = tid & 3;
#pragma unroll
    for (int m = 0; m < 16; m++) {
      int s = s0 + 4 * m;
      float d = 0.f;
      if (s < t) {
        for (int i = 0; i < 64; i++) d += Ksh[t][i] * Ksh[s][i];
        d *= bsh[t] * __expf(cumsh[t] - cumsh[s]);
      }
      Msh[t][s] = d;
    }
  }
  __syncthreads();
  // RHS preload: UW[t][j<64] = b_t*V[t][j]; UW[t][64+j] = b_t*Gamma_t*K[t][j]
  for (int idx = tid; idx < 8192; idx += 256) {
    int t = idx >> 7, j = idx & 127;
    float r;
    if (j < 64) r = bsh[t] * vhat[kbase + t * 64 + j];
    else r = bsh[t] * Gsh[t] * Ksh[t][j - 64];
    UW[t][j] = r;
  }
  __syncthreads();
  // forward substitution: row t -= M[t][s<t] * row s
  for (int t = 1; t < 64; t++) {
    if (tid < 128) {
      float acc = 0.f;
      for (int s = 0; s < t; s++) acc += Msh[t][s] * UW[s][tid];
      UW[t][tid] -= acc;
    }
    __syncthreads();
  }
  size_t ub = (size_t)(bh * 32 + ch) * 4096;
  for (int idx = tid; idx < 4096; idx += 256) {
    int t = idx >> 6, j = idx & 63;
    Ubuf[ub + idx] = UW[t][j];
    Wbuf[ub + idx] = UW[t][64 + j];
  }
}

// Phase B (sequential over chunks): grid 128 = bh*4 + vblock(16 cols).
//   Delta' = (Gend/Gt)*(U - W S_in);  S_out = Gend*S_in + K^T Delta'
//   stores S_in per chunk for phase C.
__global__ __launch_bounds__(256) void k_chunkB(
    const float* __restrict__ khat, const float* __restrict__ cumbuf,
    const float* __restrict__ Ubuf, const float* __restrict__ Wbuf,
    float* __restrict__ Sch) {
  int bid = blockIdx.x;
  int bh = bid >> 2, vb = bid & 3;
  int j0 = vb * 16;
  int tid = threadIdx.x;
  __shared__ float Wsh[64][65], Ksh[64][65];
  __shared__ float Ssh[64][17], Dsh[64][17];
  __shared__ float cumsh[64];
  for (int idx = tid; idx < 1024; idx += 256) Ssh[idx >> 4][idx & 15] = 0.f;
  int t_ = tid & 63, q_ = tid >> 6;   // q_ 0..3 -> 4 cols each
  for (int ch = 0; ch < 32; ch++) {
    size_t cb = (size_t)(bh * 32 + ch);
    size_t kbase = (size_t)bh * (2048 * 64) + (size_t)ch * 4096;
    __syncthreads();
    if (tid < 64) cumsh[tid] = cumbuf[cb * 64 + tid];
    for (int idx = tid; idx < 4096; idx += 256) {
      Wsh[idx >> 6][idx & 63] = Wbuf[cb * 4096 + idx];
      Ksh[idx >> 6][idx & 63] = khat[kbase + idx];
    }
    __syncthreads();
    // store S_in
    for (int idx = tid; idx < 1024; idx += 256) {
      int i = idx >> 4, j = idx & 15;
      Sch[cb * 4096 + (size_t)i * 64 + j0 + j] = Ssh[i][j];
    }
    // Delta (pre-scaled by Gend/Gt)
    {
      float sc = __expf(cumsh[63] - cumsh[t_]);
      float4 u = *(const float4*)&Ubuf[cb * 4096 + (size_t)t_ * 64 + j0 + q_ * 4];
      float a0 = 0, a1 = 0, a2 = 0, a3 = 0;
      for (int i = 0; i < 64; i++) {
        float w = Wsh[t_][i];
        a0 += w * Ssh[i][q_ * 4 + 0];
        a1 += w * Ssh[i][q_ * 4 + 1];
        a2 += w * Ssh[i][q_ * 4 + 2];
        a3 += w * Ssh[i][q_ * 4 + 3];
      }
      Dsh[t_][q_ * 4 + 0] = sc * (u.x - a0);
      Dsh[t_][q_ * 4 + 1] = sc * (u.y - a1);
      Dsh[t_][q_ * 4 + 2] = sc * (u.z - a2);
      Dsh[t_][q_ * 4 + 3] = sc * (u.w - a3);
    }
    __syncthreads();
    // S = Gend*S + K^T Delta'
    {
      float Gend = __expf(cumsh[63]);
      int i = t_;
      float b0 = 0, b1 = 0, b2 = 0, b3 = 0;
      for (int t = 0; t < 64; t++) {
        float kk = Ksh[t][i];
        b0 += kk * Dsh[t][q_ * 4 + 0];
        b1 += kk * Dsh[t][q_ * 4 + 1];
        b2 += kk * Dsh[t][q_ * 4 + 2];
        b3 += kk * Dsh[t][q_ * 4 + 3];
      }
      Ssh[i][q_ * 4 + 0] = Gend * Ssh[i][q_ * 4 + 0] + b0;
      Ssh[i][q_ * 4 + 1] = Gend * Ssh[i][q_ * 4 + 1] + b1;
      Ssh[i][q_ * 4 + 2] = Gend * Ssh[i][q_ * 4 + 2] + b2;
      Ssh[i][q_ * 4 + 3] = Gend * Ssh[i][q_ * 4 + 3] + b3;
    }
  }
}

// Phase C (parallel, 1024 blocks): O = diag(G) Q S_in + (QK^T . decaymask) Delta
__global__ __launch_bounds__(256) void k_out(
    const float* __restrict__ qhat, const float* __restrict__ khat,
    const float* __restrict__ cumbuf, const float* __restrict__ Ubuf,
    const float* __restrict__ Wbuf, const float* __restrict__ Sch,
    float* __restrict__ o_pre) {
  int bid = blockIdx.x;
  int bh = bid >> 5, ch = bid & 31;
  int b = bh >> 4, h = bh & 15;
  int tid = threadIdx.x;
  __shared__ float B1[64][65];  // W -> Q -> P
  __shared__ float B2[64][65];  // S -> K
  __shared__ float B3[64][65];  // Delta
  __shared__ float cumsh[64];
  size_t cb = (size_t)(bh * 32 + ch);
  size_t kbase = (size_t)bh * (2048 * 64) + (size_t)ch * 4096;
  if (tid < 64) cumsh[tid] = cumbuf[cb * 64 + tid];
  for (int idx = tid; idx < 4096; idx += 256) {
    B1[idx >> 6][idx & 63] = Wbuf[cb * 4096 + idx];
    B2[idx >> 6][idx & 63] = Sch[cb * 4096 + idx];
  }
  __syncthreads();
  int t_ = tid & 63, q_ = tid >> 6;   // q_ 0..3 -> 16 cols each
  int c0 = q_ * 16;
  float acc[16], o1[16], p[16];
  // Delta = U - W S  -> B3
#pragma unroll
  for (int j = 0; j < 16; j++) acc[j] = 0.f;
  for (int i = 0; i < 64; i++) {
    float w = B1[t_][i];
#pragma unroll
    for (int j = 0; j < 16; j++) acc[j] += w * B2[i][c0 + j];
  }
#pragma unroll
  for (int j = 0; j < 16; j += 4) {
    float4 u = *(const float4*)&Ubuf[cb * 4096 + (size_t)t_ * 64 + c0 + j];
    B3[t_][c0 + j + 0] = u.x - acc[j + 0];
    B3[t_][c0 + j + 1] = u.y - acc[j + 1];
    B3[t_][c0 + j + 2] = u.z - acc[j + 2];
    B3[t_][c0 + j + 3] = u.w - acc[j + 3];
  }
  __syncthreads();
  // B1 <- Q
  for (int idx = tid; idx < 4096; idx += 256)
    B1[idx >> 6][idx & 63] = qhat[kbase + idx];
  __syncthreads();
  // O1 = Gt * (Q S)
#pragma unroll
  for (int j = 0; j < 16; j++) o1[j] = 0.f;
  for (int i = 0; i < 64; i++) {
    float qv = B1[t_][i];
#pragma unroll
    for (int j = 0; j < 16; j++) o1[j] += qv * B2[i][c0 + j];
  }
  {
    float Gt = __expf(cumsh[t_]);
#pragma unroll
    for (int j = 0; j < 16; j++) o1[j] *= Gt;
  }
  __syncthreads();
  // B2 <- K
  for (int idx = tid; idx < 4096; idx += 256)
    B2[idx >> 6][idx & 63] = khat[kbase + idx];
  __syncthreads();
  // P[t][s] = (q_t.k_s) exp(cum_t-cum_s), s<=t
#pragma unroll
  for (int m = 0; m < 16; m++) {
    int s = c0 + m;
    float d = 0.f;
    if (s <= t_) {
      for (int i = 0; i < 64; i++) d += B1[t_][i] * B2[s][i];
      d *= __expf(cumsh[t_] - cumsh[s]);
    }
    p[m] = d;
  }
  __syncthreads();
#pragma unroll
  for (int m = 0; m < 16; m++) B1[t_][c0 + m] = p[m];
  __syncthreads();
  // O = O1 + P Delta
  for (int s = 0; s < 64; s++) {
    float pv = B1[t_][s];
#pragma unroll
    for (int j = 0; j < 16; j++) o1[j] += pv * B3[s][c0 + j];
  }
  size_t ob = ((size_t)(b * 2048 + ch * 64 + t_)) * 1024 + h * 64 + c0;
#pragma unroll
  for (int j = 0; j < 16; j += 4) {
    float4 o4 = {o1[j], o1[j + 1], o1[j + 2], o1[j + 3]};
    *(float4*)&o_pre[ob + j] = o4;
  }
}

// ---------------------------------------------------------------------------
// epilogue: per-(m,h) RMSNorm(64, eps 1e-5, mean) * gnorm_w * silu(g) -> bf16
__global__ __launch_bounds__(256) void k_gatenorm(const float* __restrict__ o_pre,
    const float* __restrict__ g, const float* __restrict__ gnw,
    __bf16* __restrict__ obf) {
  int m = blockIdx.x;
  int tid = threadIdx.x;
  size_t baseo = (size_t)m * 1024 + tid * 4;
  float4 ov = *(const float4*)&o_pre[baseo];
  float ss = ov.x * ov.x + ov.y * ov.y + ov.z * ov.z + ov.w * ov.w;
  ss += __shfl_xor(ss, 1);
  ss += __shfl_xor(ss, 2);
  ss += __shfl_xor(ss, 4);
  ss += __shfl_xor(ss, 8);
  float inv = rsqrtf(ss * (1.f / 64.f) + 1e-5f);
  float4 gv = *(const float4*)&g[baseo];
  int d0 = (tid & 15) * 4;
  float r0 = ov.x * inv * gnw[d0 + 0] * (gv.x * (1.f / (1.f + __expf(-gv.x))));
  float r1 = ov.y * inv * gnw[d0 + 1] * (gv.y * (1.f / (1.f + __expf(-gv.y))));
  float r2 = ov.z * inv * gnw[d0 + 2] * (gv.z * (1.f / (1.f + __expf(-gv.z))));
  float r3 = ov.w * inv * gnw[d0 + 3] * (gv.w * (1.f / (1.f + __expf(-gv.w))));
  bf16x4 o;
  o.x = (__bf16)r0; o.y = (__bf16)r1; o.z = (__bf16)r2; o.w = (__bf16)r3;
  *(bf16x4*)&obf[baseo] = o;
}

// ---------------------------------------------------------------------------
extern "C" void kernel_launch(void* const* d_in, const int* in_sizes, int n_in,
                              void* d_out, int out_size, void* d_ws, size_t ws_size,
                              hipStream_t stream) {
  const float* x = (const float*)d_in[0];
  const float* Wq = (const float*)d_in[1];
  const float* Wk = (const float*)d_in[2];
  const float* Wv = (const float*)d_in[3];
  const float* Wo = (const float*)d_in[4];
  const float* Wg = (const float*)d_in[5];
  const float* Wgk = (const float*)d_in[6];
  const float* Wb = (const float*)d_in[7];
  const float* bb = (const float*)d_in[8];
  const float* A_log = (const float*)d_in[9];
  const float* cqw = (const float*)d_in[10];
  const float* ckw = (const float*)d_in[11];
  const float* cvw = (const float*)d_in[12];
  const float* gnw = (const float*)d_in[13];
  const float* dtb = (const float*)d_in[14];
  float* out = (float*)d_out;

  char* ws = (char*)d_ws;
  __bf16* xbf   = (__bf16*)(ws + 0);            // 8 MB  (later obf)
  __bf16* wq_t  = (__bf16*)(ws + 8388608);      // 2 MB  (later cumbuf)
  __bf16* wk_t  = (__bf16*)(ws + 10485760);
  __bf16* wv_t  = (__bf16*)(ws + 12582912);
  __bf16* wg_t  = (__bf16*)(ws + 14680064);
  __bf16* wo_t  = (__bf16*)(ws + 16777216);
  float* qpre   = (float*)(ws + 18874368);      // 16 MB (later o_pre)
  float* kpre   = (float*)(ws + 35651584);      // 16 MB (later Ubuf)
  float* vpre   = (float*)(ws + 52428800);      // 16 MB (later Wbuf)
  float* gbuf   = (float*)(ws + 69206016);
  float* qhat   = (float*)(ws + 85983232);
  float* khat   = (float*)(ws + 102760448);
  float* vhat   = (float*)(ws + 119537664);     // 16 MB (later Sch)
  float* gk_arr = (float*)(ws + 136314880);     // 256 KB
  float* beta_a = (float*)(ws + 136577024);     // 256 KB
  float* o_pre  = qpre;
  __bf16* obf   = xbf;
  float* cumbuf = (float*)wq_t;   // 256 KB, wq_t dead after big gemm
  float* Ubuf   = kpre;           // kpre dead after conv
  float* Wbuf   = vpre;           // vpre dead after conv
  float* Sch    = vhat;           // vhat dead after chunkA

  k_convert<<<dim3((NM * NC / 4 + 255) / 256), 256, 0, stream>>>(x, xbf, NM * NC / 4);
  dim3 tg(16, 16);
  k_transpose<<<tg, 256, 0, stream>>>(Wq, wq_t);
  k_transpose<<<tg, 256, 0, stream>>>(Wk, wk_t);
  k_transpose<<<tg, 256, 0, stream>>>(Wv, wv_t);
  k_transpose<<<tg, 256, 0, stream>>>(Wg, wg_t);
  k_transpose<<<tg, 256, 0, stream>>>(Wo, wo_t);
  k_gemm<<<dim3(NM / 128, 32), 256, 0, stream>>>(xbf, wq_t, wk_t, wv_t, wg_t,
                                                 qpre, kpre, vpre, gbuf, 8);
  k_projsmall<<<NM, 256, 0, stream>>>(x, Wgk, Wb, bb, A_log, dtb, gk_arr, beta_a);
  k_conv<<<dim3(NT / 64, NB * NH, 3), 256, 0, stream>>>(qpre, kpre, vpre, cqw, ckw,
                                                        cvw, qhat, khat, vhat);
  // chunked gated-delta scan
  k_chunkA<<<1024, 256, 0, stream>>>(khat, vhat, gk_arr, beta_a, cumbuf, Ubuf, Wbuf);
  k_chunkB<<<128, 256, 0, stream>>>(khat, cumbuf, Ubuf, Wbuf, Sch);
  k_out<<<1024, 256, 0, stream>>>(qhat, khat, cumbuf, Ubuf, Wbuf, Sch, o_pre);
  k_gatenorm<<<NM, 256, 0, stream>>>(o_pre, gbuf, gnw, obf);
  k_gemm<<<dim3(NM / 128, 8), 256, 0, stream>>>(obf, wo_t, nullptr, nullptr, nullptr,
                                                out, nullptr, nullptr, nullptr, 8);
}

// Round 4
// 717.146 us; speedup vs baseline: 1.9189x; 1.1838x over previous
//
#include <hip/hip_runtime.h>
#include <math.h>

typedef float f32x4 __attribute__((ext_vector_type(4)));
typedef __bf16 bf16x8 __attribute__((ext_vector_type(8)));
typedef __bf16 bf16x4 __attribute__((ext_vector_type(4)));

// Problem constants
static constexpr int NB = 2, NT = 2048, NC = 1024, NH = 16, ND = 64;
static constexpr int NM = NB * NT;   // 4096 rows

__device__ inline float rdlane(float v, int l) {
  return __builtin_bit_cast(float, __builtin_amdgcn_readlane(__builtin_bit_cast(int, v), l));
}

// ---------------------------------------------------------------------------
// fp32 -> bf16 convert (vectorized x4)
__global__ __launch_bounds__(256) void k_convert(const float* __restrict__ src,
                                                 __bf16* __restrict__ dst, int n4) {
  int i = blockIdx.x * 256 + threadIdx.x;
  if (i >= n4) return;
  float4 v = ((const float4*)src)[i];
  bf16x4 o;
  o.x = (__bf16)v.x; o.y = (__bf16)v.y; o.z = (__bf16)v.z; o.w = (__bf16)v.w;
  ((bf16x4*)dst)[i] = o;
}

// ---------------------------------------------------------------------------
// 1024x1024 fp32 [k][n] -> bf16 [n][k] transpose (LDS-tiled, coalesced)
__global__ __launch_bounds__(256) void k_transpose(const float* __restrict__ src,
                                                   __bf16* __restrict__ dst) {
  __shared__ float t[64][65];
  int r0 = blockIdx.y * 64, c0 = blockIdx.x * 64;
  int lr = threadIdx.x >> 6;   // 0..3
  int lc = threadIdx.x & 63;
#pragma unroll
  for (int j = 0; j < 16; j++) {
    int r = j * 4 + lr;
    t[r][lc] = src[(size_t)(r0 + r) * 1024 + c0 + lc];
  }
  __syncthreads();
#pragma unroll
  for (int j = 0; j < 16; j++) {
    int r = j * 4 + lr;
    dst[(size_t)(c0 + r) * 1024 + r0 + lc] = (__bf16)t[lc][r];
  }
}

// ---------------------------------------------------------------------------
// bf16 MFMA GEMM: C[M,1024] = A[M,1024] @ B^T (B stored [n][k] bf16), fp32 out
__global__ __launch_bounds__(256) void k_gemm(const __bf16* __restrict__ A,
    const __bf16* B0, const __bf16* B1, const __bf16* B2, const __bf16* B3,
    float* C0, float* C1, float* C2, float* C3, int nblkPer) {
  constexpr int Kd = 1024;
  int mblk = blockIdx.x;
  int yb = blockIdx.y;
  int sel = yb / nblkPer;
  int nb = yb % nblkPer;
  const __bf16* Bt = sel == 0 ? B0 : sel == 1 ? B1 : sel == 2 ? B2 : B3;
  float* Cp = sel == 0 ? C0 : sel == 1 ? C1 : sel == 2 ? C2 : C3;

  __shared__ __bf16 As[128 * 32];
  __shared__ __bf16 Bs[128 * 32];
  int tid = threadIdx.x;
  int lane = tid & 63;
  int w = tid >> 6;
  int wr = w >> 1, wc = w & 1;

  f32x4 acc[4][4];
#pragma unroll
  for (int r = 0; r < 4; r++)
#pragma unroll
    for (int c = 0; c < 4; c++) acc[r][c] = (f32x4){0.f, 0.f, 0.f, 0.f};

  int rowh = tid >> 2;          // 0..63
  int kcol = (tid & 3) * 8;
  const __bf16* aS = A + (size_t)(mblk * 128 + rowh) * Kd + kcol;
  const __bf16* bS = Bt + (size_t)(nb * 128 + rowh) * Kd + kcol;
  int rbase = (wr * 64 + (lane & 15)) * 32 + ((lane >> 4) * 8);
  int cbase = (wc * 64 + (lane & 15)) * 32 + ((lane >> 4) * 8);

  for (int kt = 0; kt < Kd; kt += 32) {
    uint4 a0 = *(const uint4*)(aS + kt);
    uint4 a1 = *(const uint4*)(aS + (size_t)64 * Kd + kt);
    uint4 b0 = *(const uint4*)(bS + kt);
    uint4 b1 = *(const uint4*)(bS + (size_t)64 * Kd + kt);
    __syncthreads();
    *(uint4*)&As[rowh * 32 + kcol] = a0;
    *(uint4*)&As[(rowh + 64) * 32 + kcol] = a1;
    *(uint4*)&Bs[rowh * 32 + kcol] = b0;
    *(uint4*)&Bs[(rowh + 64) * 32 + kcol] = b1;
    __syncthreads();
    bf16x8 af[4], bfr[4];
#pragma unroll
    for (int r = 0; r < 4; r++) af[r] = *(const bf16x8*)&As[rbase + r * 16 * 32];
#pragma unroll
    for (int c = 0; c < 4; c++) bfr[c] = *(const bf16x8*)&Bs[cbase + c * 16 * 32];
#pragma unroll
    for (int r = 0; r < 4; r++)
#pragma unroll
      for (int c = 0; c < 4; c++)
        acc[r][c] = __builtin_amdgcn_mfma_f32_16x16x32_bf16(af[r], bfr[c], acc[r][c], 0, 0, 0);
  }
  int orow = mblk * 128 + wr * 64 + ((lane >> 4) << 2);
  int ocol = nb * 128 + wc * 64 + (lane & 15);
#pragma unroll
  for (int r = 0; r < 4; r++)
#pragma unroll
    for (int c = 0; c < 4; c++)
#pragma unroll
      for (int j = 0; j < 4; j++)
        Cp[(size_t)(orow + r * 16 + j) * 1024 + ocol + c * 16] = acc[r][c][j];
}

// ---------------------------------------------------------------------------
// small projections: gk = -exp(A_log)*softplus(x@Wgk + dt_bias),
//                    beta = sigmoid(x@Wb + bb). Layout out: [b*16+h][t]
__global__ __launch_bounds__(256) void k_projsmall(const float* __restrict__ x,
    const float* __restrict__ Wgk, const float* __restrict__ Wb,
    const float* __restrict__ bb, const float* __restrict__ A_log,
    const float* __restrict__ dtb, float* __restrict__ gk_arr,
    float* __restrict__ beta_arr) {
  int m = blockIdx.x;
  int b = m >> 11, t = m & 2047;
  int tid = threadIdx.x;
  int j = tid >> 3;   // 0..31 (16 gk + 16 beta)
  int p = tid & 7;
  const float* xr = x + (size_t)m * 1024;
  const float* Wcol;
  int jj;
  if (j < 16) { Wcol = Wgk; jj = j; } else { Wcol = Wb; jj = j - 16; }
  float s = 0.f;
  for (int i = p; i < 1024; i += 8) s += xr[i] * Wcol[i * 16 + jj];
  s += __shfl_xor(s, 1);
  s += __shfl_xor(s, 2);
  s += __shfl_xor(s, 4);
  if (p == 0) {
    if (j < 16) {
      float v = s + dtb[jj];
      float sp = v > 20.f ? v : log1pf(__expf(v));
      gk_arr[((size_t)(b * 16 + jj)) * 2048 + t] = -__expf(A_log[jj]) * sp;
    } else {
      float v = s + bb[jj];
      beta_arr[((size_t)(b * 16 + jj)) * 2048 + t] = 1.f / (1.f + __expf(-v));
    }
  }
}

// ---------------------------------------------------------------------------
// depthwise causal conv(K=4) + silu; for q,k additionally l2norm + rope(32).
__global__ __launch_bounds__(256) void k_conv(
    const float* __restrict__ qpre, const float* __restrict__ kpre,
    const float* __restrict__ vpre, const float* __restrict__ cqw,
    const float* __restrict__ ckw, const float* __restrict__ cvw,
    float* __restrict__ qhat, float* __restrict__ khat, float* __restrict__ vhat) {
  int z = blockIdx.z;
  const float* src = z == 0 ? qpre : z == 1 ? kpre : vpre;
  const float* cw = z == 0 ? cqw : z == 1 ? ckw : cvw;
  float* dst = z == 0 ? qhat : z == 1 ? khat : vhat;
  int t0 = blockIdx.x * 64;
  int bh = blockIdx.y;
  int b = bh >> 4, h = bh & 15;
  int tid = threadIdx.x;
  __shared__ float tile[67 * 64];
  __shared__ float outb[64 * 64];
  for (int i = tid; i < 67 * 64; i += 256) {
    int r = i >> 6, c = i & 63;
    int t = t0 - 3 + r;
    tile[i] = (t >= 0) ? src[((size_t)(b * 2048 + t)) * 1024 + h * 64 + c] : 0.f;
  }
  __syncthreads();
  int c = tid & 63;
  int rb = (tid >> 6) * 16;
  float4 w4 = *(const float4*)&cw[(h * 64 + c) * 4];
  size_t obase = ((size_t)bh) * 2048 * 64;
#pragma unroll
  for (int rr = 0; rr < 16; rr++) {
    int r = rb + rr;
    float y = tile[r * 64 + c] * w4.x + tile[(r + 1) * 64 + c] * w4.y +
              tile[(r + 2) * 64 + c] * w4.z + tile[(r + 3) * 64 + c] * w4.w;
    float sv = y * (1.f / (1.f + __expf(-y)));
    if (z == 2) dst[obase + (size_t)(t0 + r) * 64 + c] = sv;
    else outb[r * 64 + c] = sv;
  }
  if (z == 2) return;
  __syncthreads();
  int r = tid >> 2;
  int p = tid & 3;
  float ss = 0.f;
#pragma unroll
  for (int i2 = 0; i2 < 16; i2++) { float vv = outb[r * 64 + p * 16 + i2]; ss += vv * vv; }
  ss += __shfl_xor(ss, 1);
  ss += __shfl_xor(ss, 2);
  float inv = rsqrtf(ss + 1e-6f);
  int tg = t0 + r;
#pragma unroll
  for (int i2 = 0; i2 < 16; i2++) {
    int cc = p * 16 + i2;
    float val = outb[r * 64 + cc] * inv;
    float res;
    if (cc < 16) {
      float x2 = outb[r * 64 + cc + 16] * inv;
      float ang = tg * __expf(-0.5756462732485114f * cc);   // ln(1e4)/16
      float sn, cn; sincosf(ang, &sn, &cn);
      res = val * cn - x2 * sn;
    } else if (cc < 32) {
      float x1 = outb[r * 64 + cc - 16] * inv;
      float ang = tg * __expf(-0.5756462732485114f * (cc - 16));
      float sn, cn; sincosf(ang, &sn, &cn);
      res = val * cn + x1 * sn;
    } else res = val;
    dst[obase + (size_t)tg * 64 + cc] = res;
  }
}

// ---------------------------------------------------------------------------
// Chunked gated-delta. Chunk L=64, NCH=32 chunks per bh, 32 bh.
// Phase A (parallel, 1024 blocks = bh*32+ch):
//   cum_t = inclusive cumsum(g); M[t][s] = b_t exp(cum_t-cum_s) (k_t.k_s), s<t
//   Solve (I+M)[U|W] = [diag(b)V | diag(b*Gamma)K]  (forward substitution)
__global__ __launch_bounds__(256) void k_chunkA(
    const float* __restrict__ khat, const float* __restrict__ vhat,
    const float* __restrict__ gk_arr, const float* __restrict__ beta_arr,
    float* __restrict__ cumbuf, float* __restrict__ Ubuf, float* __restrict__ Wbuf) {
  int bid = blockIdx.x;
  int bh = bid >> 5, ch = bid & 31;
  int tid = threadIdx.x;
  __shared__ float Ksh[64][65];
  __shared__ float Msh[64][65];
  __shared__ float UW[64][130];
  __shared__ float cumsh[64], bsh[64], Gsh[64];
  size_t kbase = (size_t)bh * (2048 * 64) + (size_t)ch * 4096;
  size_t gb = (size_t)bh * 2048 + ch * 64;
  if (tid < 64) {
    cumsh[tid] = gk_arr[gb + tid];   // temporarily raw g
    bsh[tid] = beta_arr[gb + tid];
  }
  for (int idx = tid; idx < 4096; idx += 256) {
    Ksh[idx >> 6][idx & 63] = khat[kbase + idx];
  }
  __syncthreads();
  if (tid == 0) {
    float a = 0.f;
    for (int t = 0; t < 64; t++) { a += cumsh[t]; cumsh[t] = a; }
  }
  __syncthreads();
  if (tid < 64) {
    Gsh[tid] = __expf(cumsh[tid]);
    cumbuf[(size_t)(bh * 32 + ch) * 64 + tid] = cumsh[tid];
  }
  // M (strictly lower)
  {
    int t = tid >> 2, s0 = tid & 3;
#pragma unroll
    for (int m = 0; m < 16; m++) {
      int s = s0 + 4 * m;
      float d = 0.f;
      if (s < t) {
        for (int i = 0; i < 64; i++) d += Ksh[t][i] * Ksh[s][i];
        d *= bsh[t] * __expf(cumsh[t] - cumsh[s]);
      }
      Msh[t][s] = d;
    }
  }
  __syncthreads();
  // RHS preload: UW[t][j<64] = b_t*V[t][j]; UW[t][64+j] = b_t*Gamma_t*K[t][j]
  for (int idx = tid; idx < 8192; idx += 256) {
    int t = idx >> 7, j = idx & 127;
    float r;
    if (j < 64) r = bsh[t] * vhat[kbase + t * 64 + j];
    else r = bsh[t] * Gsh[t] * Ksh[t][j - 64];
    UW[t][j] = r;
  }
  __syncthreads();
  // forward substitution: row t -= M[t][s<t] * row s
  for (int t = 1; t < 64; t++) {
    if (tid < 128) {
      float acc = 0.f;
      for (int s = 0; s < t; s++) acc += Msh[t][s] * UW[s][tid];
      UW[t][tid] -= acc;
    }
    __syncthreads();
  }
  size_t ub = (size_t)(bh * 32 + ch) * 4096;
  for (int idx = tid; idx < 4096; idx += 256) {
    int t = idx >> 6, j = idx & 63;
    Ubuf[ub + idx] = UW[t][j];
    Wbuf[ub + idx] = UW[t][64 + j];
  }
}

// ---------------------------------------------------------------------------
// Phase B (sequential over chunks): grid 256 = bh*8 + vblock(8 cols).
// S in REGISTERS: lane l of wave q holds S[l][c0..c0+1], c0 = vb*8 + q*2.
// Cross-lane via v_readlane (VALU pipe, not LDS). K staged in LDS (column
// reads conflict-free at stride 68). W row in 64 VGPRs per lane.
//   Delta' = (Gend/Gt)*(U - W S_in);  S_out = Gend*S_in + K^T Delta'
// Stores S_in per chunk COLUMN-MAJOR: Sch[cb][j*64 + i] = S_in[i][j].
__global__ __launch_bounds__(256) void k_chunkB(
    const float* __restrict__ khat, const float* __restrict__ cumbuf,
    const float* __restrict__ Ubuf, const float* __restrict__ Wbuf,
    float* __restrict__ Sch) {
  int bid = blockIdx.x;
  int bh = bid >> 3, vb = bid & 7;
  int tid = threadIdx.x;
  int lane = tid & 63, q_ = tid >> 6;
  int c0 = vb * 8 + q_ * 2;
  __shared__ float Ksh[64 * 68];
  float S0 = 0.f, S1 = 0.f;
  for (int ch = 0; ch < 32; ch++) {
    size_t cb = (size_t)(bh * 32 + ch);
    size_t kbase = (size_t)bh * (2048 * 64) + (size_t)ch * 4096;
    __syncthreads();   // previous update done reading Ksh
    // stage K rows -> LDS (float4), row stride 68 floats (16B-aligned, and
    // column reads K[t][lane] land on distinct banks: (4t+lane)%32)
#pragma unroll
    for (int n4 = 0; n4 < 4; n4++) {
      int n = tid + n4 * 256;              // 0..1023 float4s
      float4 kv = *(const float4*)&khat[kbase + (size_t)n * 4];
      int row = n >> 4, col = (n & 15) * 4;
      *(float4*)&Ksh[row * 68 + col] = kv;
    }
    // per-lane loads: cum, U, W row (all independent of LDS)
    float cumv = cumbuf[cb * 64 + lane];
    float cum63 = rdlane(cumv, 63);
    float sc = __expf(cum63 - cumv);
    float Gend = __expf(cum63);
    float2 uv = *(const float2*)&Ubuf[cb * 4096 + (size_t)lane * 64 + c0];
    float Wrow[64];
#pragma unroll
    for (int i4 = 0; i4 < 16; i4++) {
      float4 wv = *(const float4*)&Wbuf[cb * 4096 + (size_t)lane * 64 + i4 * 4];
      Wrow[i4 * 4 + 0] = wv.x; Wrow[i4 * 4 + 1] = wv.y;
      Wrow[i4 * 4 + 2] = wv.z; Wrow[i4 * 4 + 3] = wv.w;
    }
    // store S_in (column-major, coalesced across lanes)
    Sch[cb * 4096 + (size_t)(c0 + 0) * 64 + lane] = S0;
    Sch[cb * 4096 + (size_t)(c0 + 1) * 64 + lane] = S1;
    // Delta'[lane][c] = sc * (U - sum_i W[lane][i] * S[i][c])
    float a0 = 0.f, a1 = 0.f;
#pragma unroll
    for (int i = 0; i < 64; i++) {
      float s0 = rdlane(S0, i), s1 = rdlane(S1, i);
      a0 += Wrow[i] * s0;
      a1 += Wrow[i] * s1;
    }
    float D0 = sc * (uv.x - a0);
    float D1 = sc * (uv.y - a1);
    __syncthreads();   // Ksh staged
    // S[lane][c] = Gend*S + sum_t K[t][lane] * Delta'[t][c]
    float n0 = 0.f, n1 = 0.f;
#pragma unroll
    for (int t = 0; t < 64; t++) {
      float d0 = rdlane(D0, t), d1 = rdlane(D1, t);
      float kk = Ksh[t * 68 + lane];
      n0 += kk * d0;
      n1 += kk * d1;
    }
    S0 = Gend * S0 + n0;
    S1 = Gend * S1 + n1;
  }
}

// Phase C (parallel, 1024 blocks): O = diag(G) Q S_in + (QK^T . decaymask) Delta
__global__ __launch_bounds__(256) void k_out(
    const float* __restrict__ qhat, const float* __restrict__ khat,
    const float* __restrict__ cumbuf, const float* __restrict__ Ubuf,
    const float* __restrict__ Wbuf, const float* __restrict__ Sch,
    float* __restrict__ o_pre) {
  int bid = blockIdx.x;
  int bh = bid >> 5, ch = bid & 31;
  int b = bh >> 4, h = bh & 15;
  int tid = threadIdx.x;
  __shared__ float B1[64][65];  // W -> Q -> P
  __shared__ float B2[64][65];  // S -> K
  __shared__ float B3[64][65];  // Delta
  __shared__ float cumsh[64];
  size_t cb = (size_t)(bh * 32 + ch);
  size_t kbase = (size_t)bh * (2048 * 64) + (size_t)ch * 4096;
  if (tid < 64) cumsh[tid] = cumbuf[cb * 64 + tid];
  for (int idx = tid; idx < 4096; idx += 256) {
    B1[idx >> 6][idx & 63] = Wbuf[cb * 4096 + idx];
    B2[idx & 63][idx >> 6] = Sch[cb * 4096 + idx];   // Sch is column-major
  }
  __syncthreads();
  int t_ = tid & 63, q_ = tid >> 6;   // q_ 0..3 -> 16 cols each
  int c0 = q_ * 16;
  float acc[16], o1[16], p[16];
  // Delta = U - W S  -> B3
#pragma unroll
  for (int j = 0; j < 16; j++) acc[j] = 0.f;
  for (int i = 0; i < 64; i++) {
    float w = B1[t_][i];
#pragma unroll
    for (int j = 0; j < 16; j++) acc[j] += w * B2[i][c0 + j];
  }
#pragma unroll
  for (int j = 0; j < 16; j += 4) {
    float4 u = *(const float4*)&Ubuf[cb * 4096 + (size_t)t_ * 64 + c0 + j];
    B3[t_][c0 + j + 0] = u.x - acc[j + 0];
    B3[t_][c0 + j + 1] = u.y - acc[j + 1];
    B3[t_][c0 + j + 2] = u.z - acc[j + 2];
    B3[t_][c0 + j + 3] = u.w - acc[j + 3];
  }
  __syncthreads();
  // B1 <- Q
  for (int idx = tid; idx < 4096; idx += 256)
    B1[idx >> 6][idx & 63] = qhat[kbase + idx];
  __syncthreads();
  // O1 = Gt * (Q S)
#pragma unroll
  for (int j = 0; j < 16; j++) o1[j] = 0.f;
  for (int i = 0; i < 64; i++) {
    float qv = B1[t_][i];
#pragma unroll
    for (int j = 0; j < 16; j++) o1[j] += qv * B2[i][c0 + j];
  }
  {
    float Gt = __expf(cumsh[t_]);
#pragma unroll
    for (int j = 0; j < 16; j++) o1[j] *= Gt;
  }
  __syncthreads();
  // B2 <- K
  for (int idx = tid; idx < 4096; idx += 256)
    B2[idx >> 6][idx & 63] = khat[kbase + idx];
  __syncthreads();
  // P[t][s] = (q_t.k_s) exp(cum_t-cum_s), s<=t
#pragma unroll
  for (int m = 0; m < 16; m++) {
    int s = c0 + m;
    float d = 0.f;
    if (s <= t_) {
      for (int i = 0; i < 64; i++) d += B1[t_][i] * B2[s][i];
      d *= __expf(cumsh[t_] - cumsh[s]);
    }
    p[m] = d;
  }
  __syncthreads();
#pragma unroll
  for (int m = 0; m < 16; m++) B1[t_][c0 + m] = p[m];
  __syncthreads();
  // O = O1 + P Delta
  for (int s = 0; s < 64; s++) {
    float pv = B1[t_][s];
#pragma unroll
    for (int j = 0; j < 16; j++) o1[j] += pv * B3[s][c0 + j];
  }
  size_t ob = ((size_t)(b * 2048 + ch * 64 + t_)) * 1024 + h * 64 + c0;
#pragma unroll
  for (int j = 0; j < 16; j += 4) {
    float4 o4 = {o1[j], o1[j + 1], o1[j + 2], o1[j + 3]};
    *(float4*)&o_pre[ob + j] = o4;
  }
}

// ---------------------------------------------------------------------------
// epilogue: per-(m,h) RMSNorm(64, eps 1e-5, mean) * gnorm_w * silu(g) -> bf16
__global__ __launch_bounds__(256) void k_gatenorm(const float* __restrict__ o_pre,
    const float* __restrict__ g, const float* __restrict__ gnw,
    __bf16* __restrict__ obf) {
  int m = blockIdx.x;
  int tid = threadIdx.x;
  size_t baseo = (size_t)m * 1024 + tid * 4;
  float4 ov = *(const float4*)&o_pre[baseo];
  float ss = ov.x * ov.x + ov.y * ov.y + ov.z * ov.z + ov.w * ov.w;
  ss += __shfl_xor(ss, 1);
  ss += __shfl_xor(ss, 2);
  ss += __shfl_xor(ss, 4);
  ss += __shfl_xor(ss, 8);
  float inv = rsqrtf(ss * (1.f / 64.f) + 1e-5f);
  float4 gv = *(const float4*)&g[baseo];
  int d0 = (tid & 15) * 4;
  float r0 = ov.x * inv * gnw[d0 + 0] * (gv.x * (1.f / (1.f + __expf(-gv.x))));
  float r1 = ov.y * inv * gnw[d0 + 1] * (gv.y * (1.f / (1.f + __expf(-gv.y))));
  float r2 = ov.z * inv * gnw[d0 + 2] * (gv.z * (1.f / (1.f + __expf(-gv.z))));
  float r3 = ov.w * inv * gnw[d0 + 3] * (gv.w * (1.f / (1.f + __expf(-gv.w))));
  bf16x4 o;
  o.x = (__bf16)r0; o.y = (__bf16)r1; o.z = (__bf16)r2; o.w = (__bf16)r3;
  *(bf16x4*)&obf[baseo] = o;
}

// ---------------------------------------------------------------------------
extern "C" void kernel_launch(void* const* d_in, const int* in_sizes, int n_in,
                              void* d_out, int out_size, void* d_ws, size_t ws_size,
                              hipStream_t stream) {
  const float* x = (const float*)d_in[0];
  const float* Wq = (const float*)d_in[1];
  const float* Wk = (const float*)d_in[2];
  const float* Wv = (const float*)d_in[3];
  const float* Wo = (const float*)d_in[4];
  const float* Wg = (const float*)d_in[5];
  const float* Wgk = (const float*)d_in[6];
  const float* Wb = (const float*)d_in[7];
  const float* bb = (const float*)d_in[8];
  const float* A_log = (const float*)d_in[9];
  const float* cqw = (const float*)d_in[10];
  const float* ckw = (const float*)d_in[11];
  const float* cvw = (const float*)d_in[12];
  const float* gnw = (const float*)d_in[13];
  const float* dtb = (const float*)d_in[14];
  float* out = (float*)d_out;

  char* ws = (char*)d_ws;
  __bf16* xbf   = (__bf16*)(ws + 0);            // 8 MB  (later obf)
  __bf16* wq_t  = (__bf16*)(ws + 8388608);      // 2 MB  (later cumbuf)
  __bf16* wk_t  = (__bf16*)(ws + 10485760);
  __bf16* wv_t  = (__bf16*)(ws + 12582912);
  __bf16* wg_t  = (__bf16*)(ws + 14680064);
  __bf16* wo_t  = (__bf16*)(ws + 16777216);
  float* qpre   = (float*)(ws + 18874368);      // 16 MB (later o_pre)
  float* kpre   = (float*)(ws + 35651584);      // 16 MB (later Ubuf)
  float* vpre   = (float*)(ws + 52428800);      // 16 MB (later Wbuf)
  float* gbuf   = (float*)(ws + 69206016);
  float* qhat   = (float*)(ws + 85983232);
  float* khat   = (float*)(ws + 102760448);
  float* vhat   = (float*)(ws + 119537664);     // 16 MB (later Sch)
  float* gk_arr = (float*)(ws + 136314880);     // 256 KB
  float* beta_a = (float*)(ws + 136577024);     // 256 KB
  float* o_pre  = qpre;
  __bf16* obf   = xbf;
  float* cumbuf = (float*)wq_t;   // 256 KB, wq_t dead after big gemm
  float* Ubuf   = kpre;           // kpre dead after conv
  float* Wbuf   = vpre;           // vpre dead after conv
  float* Sch    = vhat;           // vhat dead after chunkA

  k_convert<<<dim3((NM * NC / 4 + 255) / 256), 256, 0, stream>>>(x, xbf, NM * NC / 4);
  dim3 tg(16, 16);
  k_transpose<<<tg, 256, 0, stream>>>(Wq, wq_t);
  k_transpose<<<tg, 256, 0, stream>>>(Wk, wk_t);
  k_transpose<<<tg, 256, 0, stream>>>(Wv, wv_t);
  k_transpose<<<tg, 256, 0, stream>>>(Wg, wg_t);
  k_transpose<<<tg, 256, 0, stream>>>(Wo, wo_t);
  k_gemm<<<dim3(NM / 128, 32), 256, 0, stream>>>(xbf, wq_t, wk_t, wv_t, wg_t,
                                                 qpre, kpre, vpre, gbuf, 8);
  k_projsmall<<<NM, 256, 0, stream>>>(x, Wgk, Wb, bb, A_log, dtb, gk_arr, beta_a);
  k_conv<<<dim3(NT / 64, NB * NH, 3), 256, 0, stream>>>(qpre, kpre, vpre, cqw, ckw,
                                                        cvw, qhat, khat, vhat);
  // chunked gated-delta scan
  k_chunkA<<<1024, 256, 0, stream>>>(khat, vhat, gk_arr, beta_a, cumbuf, Ubuf, Wbuf);
  k_chunkB<<<256, 256, 0, stream>>>(khat, cumbuf, Ubuf, Wbuf, Sch);
  k_out<<<1024, 256, 0, stream>>>(qhat, khat, cumbuf, Ubuf, Wbuf, Sch, o_pre);
  k_gatenorm<<<NM, 256, 0, stream>>>(o_pre, gbuf, gnw, obf);
  k_gemm<<<dim3(NM / 128, 8), 256, 0, stream>>>(obf, wo_t, nullptr, nullptr, nullptr,
                                                out, nullptr, nullptr, nullptr, 8);
}

// Round 5
// 611.568 us; speedup vs baseline: 2.2501x; 1.1726x over previous
//
#include <hip/hip_runtime.h>
#include <math.h>

typedef float f32x4 __attribute__((ext_vector_type(4)));
typedef __bf16 bf16x8 __attribute__((ext_vector_type(8)));
typedef __bf16 bf16x4 __attribute__((ext_vector_type(4)));

// Problem constants
static constexpr int NB = 2, NT = 2048, NC = 1024, NH = 16, ND = 64;
static constexpr int NM = NB * NT;   // 4096 rows

__device__ inline float rdlane(float v, int l) {
  return __builtin_bit_cast(float, __builtin_amdgcn_readlane(__builtin_bit_cast(int, v), l));
}

// ---------------------------------------------------------------------------
// fp32 -> bf16 convert (vectorized x4)
__global__ __launch_bounds__(256) void k_convert(const float* __restrict__ src,
                                                 __bf16* __restrict__ dst, int n4) {
  int i = blockIdx.x * 256 + threadIdx.x;
  if (i >= n4) return;
  float4 v = ((const float4*)src)[i];
  bf16x4 o;
  o.x = (__bf16)v.x; o.y = (__bf16)v.y; o.z = (__bf16)v.z; o.w = (__bf16)v.w;
  ((bf16x4*)dst)[i] = o;
}

// ---------------------------------------------------------------------------
// 1024x1024 fp32 [k][n] -> bf16 [n][k] transpose (LDS-tiled, coalesced)
__global__ __launch_bounds__(256) void k_transpose(const float* __restrict__ src,
                                                   __bf16* __restrict__ dst) {
  __shared__ float t[64][65];
  int r0 = blockIdx.y * 64, c0 = blockIdx.x * 64;
  int lr = threadIdx.x >> 6;   // 0..3
  int lc = threadIdx.x & 63;
#pragma unroll
  for (int j = 0; j < 16; j++) {
    int r = j * 4 + lr;
    t[r][lc] = src[(size_t)(r0 + r) * 1024 + c0 + lc];
  }
  __syncthreads();
#pragma unroll
  for (int j = 0; j < 16; j++) {
    int r = j * 4 + lr;
    dst[(size_t)(c0 + r) * 1024 + r0 + lc] = (__bf16)t[lc][r];
  }
}

// ---------------------------------------------------------------------------
// bf16 MFMA GEMM: C[M,1024] = A[M,1024] @ B^T (B stored [n][k] bf16), fp32 out
__global__ __launch_bounds__(256) void k_gemm(const __bf16* __restrict__ A,
    const __bf16* B0, const __bf16* B1, const __bf16* B2, const __bf16* B3,
    float* C0, float* C1, float* C2, float* C3, int nblkPer) {
  constexpr int Kd = 1024;
  int mblk = blockIdx.x;
  int yb = blockIdx.y;
  int sel = yb / nblkPer;
  int nb = yb % nblkPer;
  const __bf16* Bt = sel == 0 ? B0 : sel == 1 ? B1 : sel == 2 ? B2 : B3;
  float* Cp = sel == 0 ? C0 : sel == 1 ? C1 : sel == 2 ? C2 : C3;

  __shared__ __bf16 As[128 * 32];
  __shared__ __bf16 Bs[128 * 32];
  int tid = threadIdx.x;
  int lane = tid & 63;
  int w = tid >> 6;
  int wr = w >> 1, wc = w & 1;

  f32x4 acc[4][4];
#pragma unroll
  for (int r = 0; r < 4; r++)
#pragma unroll
    for (int c = 0; c < 4; c++) acc[r][c] = (f32x4){0.f, 0.f, 0.f, 0.f};

  int rowh = tid >> 2;          // 0..63
  int kcol = (tid & 3) * 8;
  const __bf16* aS = A + (size_t)(mblk * 128 + rowh) * Kd + kcol;
  const __bf16* bS = Bt + (size_t)(nb * 128 + rowh) * Kd + kcol;
  int rbase = (wr * 64 + (lane & 15)) * 32 + ((lane >> 4) * 8);
  int cbase = (wc * 64 + (lane & 15)) * 32 + ((lane >> 4) * 8);

  for (int kt = 0; kt < Kd; kt += 32) {
    uint4 a0 = *(const uint4*)(aS + kt);
    uint4 a1 = *(const uint4*)(aS + (size_t)64 * Kd + kt);
    uint4 b0 = *(const uint4*)(bS + kt);
    uint4 b1 = *(const uint4*)(bS + (size_t)64 * Kd + kt);
    __syncthreads();
    *(uint4*)&As[rowh * 32 + kcol] = a0;
    *(uint4*)&As[(rowh + 64) * 32 + kcol] = a1;
    *(uint4*)&Bs[rowh * 32 + kcol] = b0;
    *(uint4*)&Bs[(rowh + 64) * 32 + kcol] = b1;
    __syncthreads();
    bf16x8 af[4], bfr[4];
#pragma unroll
    for (int r = 0; r < 4; r++) af[r] = *(const bf16x8*)&As[rbase + r * 16 * 32];
#pragma unroll
    for (int c = 0; c < 4; c++) bfr[c] = *(const bf16x8*)&Bs[cbase + c * 16 * 32];
#pragma unroll
    for (int r = 0; r < 4; r++)
#pragma unroll
      for (int c = 0; c < 4; c++)
        acc[r][c] = __builtin_amdgcn_mfma_f32_16x16x32_bf16(af[r], bfr[c], acc[r][c], 0, 0, 0);
  }
  int orow = mblk * 128 + wr * 64 + ((lane >> 4) << 2);
  int ocol = nb * 128 + wc * 64 + (lane & 15);
#pragma unroll
  for (int r = 0; r < 4; r++)
#pragma unroll
    for (int c = 0; c < 4; c++)
#pragma unroll
      for (int j = 0; j < 4; j++)
        Cp[(size_t)(orow + r * 16 + j) * 1024 + ocol + c * 16] = acc[r][c][j];
}

// ---------------------------------------------------------------------------
// small projections: gk = -exp(A_log)*softplus(x@Wgk + dt_bias),
//                    beta = sigmoid(x@Wb + bb). Layout out: [b*16+h][t]
__global__ __launch_bounds__(256) void k_projsmall(const float* __restrict__ x,
    const float* __restrict__ Wgk, const float* __restrict__ Wb,
    const float* __restrict__ bb, const float* __restrict__ A_log,
    const float* __restrict__ dtb, float* __restrict__ gk_arr,
    float* __restrict__ beta_arr) {
  int m = blockIdx.x;
  int b = m >> 11, t = m & 2047;
  int tid = threadIdx.x;
  int j = tid >> 3;   // 0..31 (16 gk + 16 beta)
  int p = tid & 7;
  const float* xr = x + (size_t)m * 1024;
  const float* Wcol;
  int jj;
  if (j < 16) { Wcol = Wgk; jj = j; } else { Wcol = Wb; jj = j - 16; }
  float s = 0.f;
  for (int i = p; i < 1024; i += 8) s += xr[i] * Wcol[i * 16 + jj];
  s += __shfl_xor(s, 1);
  s += __shfl_xor(s, 2);
  s += __shfl_xor(s, 4);
  if (p == 0) {
    if (j < 16) {
      float v = s + dtb[jj];
      float sp = v > 20.f ? v : log1pf(__expf(v));
      gk_arr[((size_t)(b * 16 + jj)) * 2048 + t] = -__expf(A_log[jj]) * sp;
    } else {
      float v = s + bb[jj];
      beta_arr[((size_t)(b * 16 + jj)) * 2048 + t] = 1.f / (1.f + __expf(-v));
    }
  }
}

// ---------------------------------------------------------------------------
// depthwise causal conv(K=4) + silu; for q,k additionally l2norm + rope(32).
__global__ __launch_bounds__(256) void k_conv(
    const float* __restrict__ qpre, const float* __restrict__ kpre,
    const float* __restrict__ vpre, const float* __restrict__ cqw,
    const float* __restrict__ ckw, const float* __restrict__ cvw,
    float* __restrict__ qhat, float* __restrict__ khat, float* __restrict__ vhat) {
  int z = blockIdx.z;
  const float* src = z == 0 ? qpre : z == 1 ? kpre : vpre;
  const float* cw = z == 0 ? cqw : z == 1 ? ckw : cvw;
  float* dst = z == 0 ? qhat : z == 1 ? khat : vhat;
  int t0 = blockIdx.x * 64;
  int bh = blockIdx.y;
  int b = bh >> 4, h = bh & 15;
  int tid = threadIdx.x;
  __shared__ float tile[67 * 64];
  __shared__ float outb[64 * 64];
  for (int i = tid; i < 67 * 64; i += 256) {
    int r = i >> 6, c = i & 63;
    int t = t0 - 3 + r;
    tile[i] = (t >= 0) ? src[((size_t)(b * 2048 + t)) * 1024 + h * 64 + c] : 0.f;
  }
  __syncthreads();
  int c = tid & 63;
  int rb = (tid >> 6) * 16;
  float4 w4 = *(const float4*)&cw[(h * 64 + c) * 4];
  size_t obase = ((size_t)bh) * 2048 * 64;
#pragma unroll
  for (int rr = 0; rr < 16; rr++) {
    int r = rb + rr;
    float y = tile[r * 64 + c] * w4.x + tile[(r + 1) * 64 + c] * w4.y +
              tile[(r + 2) * 64 + c] * w4.z + tile[(r + 3) * 64 + c] * w4.w;
    float sv = y * (1.f / (1.f + __expf(-y)));
    if (z == 2) dst[obase + (size_t)(t0 + r) * 64 + c] = sv;
    else outb[r * 64 + c] = sv;
  }
  if (z == 2) return;
  __syncthreads();
  int r = tid >> 2;
  int p = tid & 3;
  float ss = 0.f;
#pragma unroll
  for (int i2 = 0; i2 < 16; i2++) { float vv = outb[r * 64 + p * 16 + i2]; ss += vv * vv; }
  ss += __shfl_xor(ss, 1);
  ss += __shfl_xor(ss, 2);
  float inv = rsqrtf(ss + 1e-6f);
  int tg = t0 + r;
#pragma unroll
  for (int i2 = 0; i2 < 16; i2++) {
    int cc = p * 16 + i2;
    float val = outb[r * 64 + cc] * inv;
    float res;
    if (cc < 16) {
      float x2 = outb[r * 64 + cc + 16] * inv;
      float ang = tg * __expf(-0.5756462732485114f * cc);   // ln(1e4)/16
      float sn, cn; sincosf(ang, &sn, &cn);
      res = val * cn - x2 * sn;
    } else if (cc < 32) {
      float x1 = outb[r * 64 + cc - 16] * inv;
      float ang = tg * __expf(-0.5756462732485114f * (cc - 16));
      float sn, cn; sincosf(ang, &sn, &cn);
      res = val * cn + x1 * sn;
    } else res = val;
    dst[obase + (size_t)tg * 64 + cc] = res;
  }
}

// ---------------------------------------------------------------------------
// Chunked gated-delta, Phase A v2 (parallel, 1024 blocks = bh*32+ch):
//   cum = inclusive cumsum(g) via wave shfl-scan
//   M[t][s] = b_t exp(cum_t-cum_s) (k_t.k_s), s<t  -- K.K^T via bf16 MFMA
//   Solve (I+M)[U|W] = [diag(b)V | diag(b*Gamma)K] -- per-thread-column
//   forward substitution in registers (M rows read as broadcast float4)
__global__ __launch_bounds__(256) void k_chunkA(
    const float* __restrict__ khat, const float* __restrict__ vhat,
    const float* __restrict__ gk_arr, const float* __restrict__ beta_arr,
    float* __restrict__ cumbuf, float* __restrict__ Ubuf, float* __restrict__ Wbuf) {
  int bid = blockIdx.x;
  int bh = bid >> 5, ch = bid & 31;
  int tid = threadIdx.x;
  int lane = tid & 63, w = tid >> 6;
  __shared__ __bf16 Kbf[64 * 64];                         // 8 KB, chunk-swizzled
  __shared__ __attribute__((aligned(16))) float Msh[64 * 68];  // 17.4 KB
  __shared__ float cumsh[64], bsh[64];
  size_t kbase = (size_t)bh * (2048 * 64) + (size_t)ch * 4096;
  size_t gb = (size_t)bh * 2048 + ch * 64;
  size_t cb4096 = (size_t)(bh * 32 + ch) * 4096;

  // --- stage K as bf16, XOR-swizzled (chunk ^= row&7) to kill 128B-row conflicts
  {
    int row = tid >> 2, c16 = (tid & 3) * 16;
    const float* src = &khat[kbase + row * 64 + c16];
    float4 f0 = *(const float4*)(src + 0);
    float4 f1 = *(const float4*)(src + 4);
    float4 f2 = *(const float4*)(src + 8);
    float4 f3 = *(const float4*)(src + 12);
    bf16x8 h0, h1;
    h0[0] = (__bf16)f0.x; h0[1] = (__bf16)f0.y; h0[2] = (__bf16)f0.z; h0[3] = (__bf16)f0.w;
    h0[4] = (__bf16)f1.x; h0[5] = (__bf16)f1.y; h0[6] = (__bf16)f1.z; h0[7] = (__bf16)f1.w;
    h1[0] = (__bf16)f2.x; h1[1] = (__bf16)f2.y; h1[2] = (__bf16)f2.z; h1[3] = (__bf16)f2.w;
    h1[4] = (__bf16)f3.x; h1[5] = (__bf16)f3.y; h1[6] = (__bf16)f3.z; h1[7] = (__bf16)f3.w;
    int ch0 = ((c16 >> 3) + 0) ^ (row & 7);
    int ch1 = ((c16 >> 3) + 1) ^ (row & 7);
    *(bf16x8*)&Kbf[row * 64 + ch0 * 8] = h0;
    *(bf16x8*)&Kbf[row * 64 + ch1 * 8] = h1;
  }
  // --- zero Msh (so substitution can over-read float4 chunks safely)
  for (int i = tid; i < 64 * 68; i += 256) Msh[i] = 0.f;
  // --- g/beta load + wave-parallel inclusive scan (wave 0 only)
  if (tid < 64) {
    float g = gk_arr[gb + tid];
    float bv = beta_arr[gb + tid];
#pragma unroll
    for (int d = 1; d < 64; d <<= 1) {
      float n = __shfl_up(g, d, 64);
      if (tid >= d) g += n;
    }
    cumsh[tid] = g;
    bsh[tid] = bv;
    cumbuf[(size_t)(bh * 32 + ch) * 64 + tid] = g;
  }
  __syncthreads();

  // --- M = tril(K K^T) scaled, via MFMA. wave w owns rows 16w..16w+15.
  {
    f32x4 macc[4];
#pragma unroll
    for (int c = 0; c < 4; c++) macc[c] = (f32x4){0.f, 0.f, 0.f, 0.f};
    int arow = w * 16 + (lane & 15);
    int kb = lane >> 4;
    bf16x8 af0 = *(const bf16x8*)&Kbf[arow * 64 + ((0 + kb) ^ (arow & 7)) * 8];
    bf16x8 af1 = *(const bf16x8*)&Kbf[arow * 64 + ((4 + kb) ^ (arow & 7)) * 8];
#pragma unroll
    for (int c = 0; c < 4; c++) {
      if (c <= w) {
        int brow = c * 16 + (lane & 15);
        bf16x8 bf0 = *(const bf16x8*)&Kbf[brow * 64 + ((0 + kb) ^ (brow & 7)) * 8];
        bf16x8 bf1 = *(const bf16x8*)&Kbf[brow * 64 + ((4 + kb) ^ (brow & 7)) * 8];
        macc[c] = __builtin_amdgcn_mfma_f32_16x16x32_bf16(af0, bf0, macc[c], 0, 0, 0);
        macc[c] = __builtin_amdgcn_mfma_f32_16x16x32_bf16(af1, bf1, macc[c], 0, 0, 0);
      }
    }
    // scale + write lower tiles
    float bt[4], ct[4];
#pragma unroll
    for (int j = 0; j < 4; j++) {
      int trow = w * 16 + (lane >> 4) * 4 + j;
      bt[j] = bsh[trow];
      ct[j] = cumsh[trow];
    }
#pragma unroll
    for (int c = 0; c < 4; c++) {
      if (c <= w) {
        int scol = c * 16 + (lane & 15);
        float cums = cumsh[scol];
#pragma unroll
        for (int j = 0; j < 4; j++) {
          int trow = w * 16 + (lane >> 4) * 4 + j;
          float val = macc[c][j] * bt[j] * __expf(ct[j] - cums);
          Msh[trow * 68 + scol] = (scol < trow) ? val : 0.f;
        }
      }
    }
  }

  // --- RHS columns into registers (threads 0..127: c<64 -> U col, else W col)
  float uw[64];
  int c = tid;
  if (tid < 128) {
    bool isU = c < 64;
    int cc = c & 63;
    const float* src = isU ? &vhat[kbase + cc] : &khat[kbase + cc];
#pragma unroll
    for (int t = 0; t < 64; t++) {
      float r = src[t * 64] * bsh[t];
      if (!isU) r *= __expf(cumsh[t]);
      uw[t] = r;
    }
  }
  __syncthreads();   // Msh ready

  if (tid < 128) {
    // forward substitution, fully in registers; M row chunks broadcast
#pragma unroll
    for (int t = 1; t < 64; t++) {
      float acc = 0.f;
#pragma unroll
      for (int q = 0; q <= (t - 1) >> 2; q++) {
        float4 m4 = *(const float4*)&Msh[t * 68 + q * 4];
        acc += m4.x * uw[q * 4 + 0] + m4.y * uw[q * 4 + 1] +
               m4.z * uw[q * 4 + 2] + m4.w * uw[q * 4 + 3];
      }
      uw[t] -= acc;
    }
    bool isU = c < 64;
    int cc = c & 63;
    float* dst = isU ? &Ubuf[cb4096 + cc] : &Wbuf[cb4096 + cc];
#pragma unroll
    for (int t = 0; t < 64; t++) dst[t * 64] = uw[t];
  }
}

// ---------------------------------------------------------------------------
// Phase B (sequential over chunks): grid 256 = bh*8 + vblock(8 cols).
// S in REGISTERS: lane l of wave q holds S[l][c0..c0+1], c0 = vb*8 + q*2.
__global__ __launch_bounds__(256) void k_chunkB(
    const float* __restrict__ khat, const float* __restrict__ cumbuf,
    const float* __restrict__ Ubuf, const float* __restrict__ Wbuf,
    float* __restrict__ Sch) {
  int bid = blockIdx.x;
  int bh = bid >> 3, vb = bid & 7;
  int tid = threadIdx.x;
  int lane = tid & 63, q_ = tid >> 6;
  int c0 = vb * 8 + q_ * 2;
  __shared__ float Ksh[64 * 68];
  float S0 = 0.f, S1 = 0.f;
  for (int ch = 0; ch < 32; ch++) {
    size_t cb = (size_t)(bh * 32 + ch);
    size_t kbase = (size_t)bh * (2048 * 64) + (size_t)ch * 4096;
    __syncthreads();   // previous update done reading Ksh
#pragma unroll
    for (int n4 = 0; n4 < 4; n4++) {
      int n = tid + n4 * 256;              // 0..1023 float4s
      float4 kv = *(const float4*)&khat[kbase + (size_t)n * 4];
      int row = n >> 4, col = (n & 15) * 4;
      *(float4*)&Ksh[row * 68 + col] = kv;
    }
    float cumv = cumbuf[cb * 64 + lane];
    float cum63 = rdlane(cumv, 63);
    float sc = __expf(cum63 - cumv);
    float Gend = __expf(cum63);
    float2 uv = *(const float2*)&Ubuf[cb * 4096 + (size_t)lane * 64 + c0];
    float Wrow[64];
#pragma unroll
    for (int i4 = 0; i4 < 16; i4++) {
      float4 wv = *(const float4*)&Wbuf[cb * 4096 + (size_t)lane * 64 + i4 * 4];
      Wrow[i4 * 4 + 0] = wv.x; Wrow[i4 * 4 + 1] = wv.y;
      Wrow[i4 * 4 + 2] = wv.z; Wrow[i4 * 4 + 3] = wv.w;
    }
    Sch[cb * 4096 + (size_t)(c0 + 0) * 64 + lane] = S0;
    Sch[cb * 4096 + (size_t)(c0 + 1) * 64 + lane] = S1;
    float a0 = 0.f, a1 = 0.f;
#pragma unroll
    for (int i = 0; i < 64; i++) {
      float s0 = rdlane(S0, i), s1 = rdlane(S1, i);
      a0 += Wrow[i] * s0;
      a1 += Wrow[i] * s1;
    }
    float D0 = sc * (uv.x - a0);
    float D1 = sc * (uv.y - a1);
    __syncthreads();   // Ksh staged
    float n0 = 0.f, n1 = 0.f;
#pragma unroll
    for (int t = 0; t < 64; t++) {
      float d0 = rdlane(D0, t), d1 = rdlane(D1, t);
      float kk = Ksh[t * 68 + lane];
      n0 += kk * d0;
      n1 += kk * d1;
    }
    S0 = Gend * S0 + n0;
    S1 = Gend * S1 + n1;
  }
}

// Phase C (parallel, 1024 blocks): O = diag(G) Q S_in + (QK^T . decaymask) Delta
__global__ __launch_bounds__(256) void k_out(
    const float* __restrict__ qhat, const float* __restrict__ khat,
    const float* __restrict__ cumbuf, const float* __restrict__ Ubuf,
    const float* __restrict__ Wbuf, const float* __restrict__ Sch,
    float* __restrict__ o_pre) {
  int bid = blockIdx.x;
  int bh = bid >> 5, ch = bid & 31;
  int b = bh >> 4, h = bh & 15;
  int tid = threadIdx.x;
  __shared__ float B1[64][65];  // W -> Q -> P
  __shared__ float B2[64][65];  // S -> K
  __shared__ float B3[64][65];  // Delta
  __shared__ float cumsh[64];
  size_t cb = (size_t)(bh * 32 + ch);
  size_t kbase = (size_t)bh * (2048 * 64) + (size_t)ch * 4096;
  if (tid < 64) cumsh[tid] = cumbuf[cb * 64 + tid];
  for (int idx = tid; idx < 4096; idx += 256) {
    B1[idx >> 6][idx & 63] = Wbuf[cb * 4096 + idx];
    B2[idx & 63][idx >> 6] = Sch[cb * 4096 + idx];   // Sch is column-major
  }
  __syncthreads();
  int t_ = tid & 63, q_ = tid >> 6;   // q_ 0..3 -> 16 cols each
  int c0 = q_ * 16;
  float acc[16], o1[16], p[16];
  // Delta = U - W S  -> B3
#pragma unroll
  for (int j = 0; j < 16; j++) acc[j] = 0.f;
  for (int i = 0; i < 64; i++) {
    float w = B1[t_][i];
#pragma unroll
    for (int j = 0; j < 16; j++) acc[j] += w * B2[i][c0 + j];
  }
#pragma unroll
  for (int j = 0; j < 16; j += 4) {
    float4 u = *(const float4*)&Ubuf[cb * 4096 + (size_t)t_ * 64 + c0 + j];
    B3[t_][c0 + j + 0] = u.x - acc[j + 0];
    B3[t_][c0 + j + 1] = u.y - acc[j + 1];
    B3[t_][c0 + j + 2] = u.z - acc[j + 2];
    B3[t_][c0 + j + 3] = u.w - acc[j + 3];
  }
  __syncthreads();
  // B1 <- Q
  for (int idx = tid; idx < 4096; idx += 256)
    B1[idx >> 6][idx & 63] = qhat[kbase + idx];
  __syncthreads();
  // O1 = Gt * (Q S)
#pragma unroll
  for (int j = 0; j < 16; j++) o1[j] = 0.f;
  for (int i = 0; i < 64; i++) {
    float qv = B1[t_][i];
#pragma unroll
    for (int j = 0; j < 16; j++) o1[j] += qv * B2[i][c0 + j];
  }
  {
    float Gt = __expf(cumsh[t_]);
#pragma unroll
    for (int j = 0; j < 16; j++) o1[j] *= Gt;
  }
  __syncthreads();
  // B2 <- K
  for (int idx = tid; idx < 4096; idx += 256)
    B2[idx >> 6][idx & 63] = khat[kbase + idx];
  __syncthreads();
  // P[t][s] = (q_t.k_s) exp(cum_t-cum_s), s<=t
#pragma unroll
  for (int m = 0; m < 16; m++) {
    int s = c0 + m;
    float d = 0.f;
    if (s <= t_) {
      for (int i = 0; i < 64; i++) d += B1[t_][i] * B2[s][i];
      d *= __expf(cumsh[t_] - cumsh[s]);
    }
    p[m] = d;
  }
  __syncthreads();
#pragma unroll
  for (int m = 0; m < 16; m++) B1[t_][c0 + m] = p[m];
  __syncthreads();
  // O = O1 + P Delta
  for (int s = 0; s < 64; s++) {
    float pv = B1[t_][s];
#pragma unroll
    for (int j = 0; j < 16; j++) o1[j] += pv * B3[s][c0 + j];
  }
  size_t ob = ((size_t)(b * 2048 + ch * 64 + t_)) * 1024 + h * 64 + c0;
#pragma unroll
  for (int j = 0; j < 16; j += 4) {
    float4 o4 = {o1[j], o1[j + 1], o1[j + 2], o1[j + 3]};
    *(float4*)&o_pre[ob + j] = o4;
  }
}

// ---------------------------------------------------------------------------
// epilogue: per-(m,h) RMSNorm(64, eps 1e-5, mean) * gnorm_w * silu(g) -> bf16
__global__ __launch_bounds__(256) void k_gatenorm(const float* __restrict__ o_pre,
    const float* __restrict__ g, const float* __restrict__ gnw,
    __bf16* __restrict__ obf) {
  int m = blockIdx.x;
  int tid = threadIdx.x;
  size_t baseo = (size_t)m * 1024 + tid * 4;
  float4 ov = *(const float4*)&o_pre[baseo];
  float ss = ov.x * ov.x + ov.y * ov.y + ov.z * ov.z + ov.w * ov.w;
  ss += __shfl_xor(ss, 1);
  ss += __shfl_xor(ss, 2);
  ss += __shfl_xor(ss, 4);
  ss += __shfl_xor(ss, 8);
  float inv = rsqrtf(ss * (1.f / 64.f) + 1e-5f);
  float4 gv = *(const float4*)&g[baseo];
  int d0 = (tid & 15) * 4;
  float r0 = ov.x * inv * gnw[d0 + 0] * (gv.x * (1.f / (1.f + __expf(-gv.x))));
  float r1 = ov.y * inv * gnw[d0 + 1] * (gv.y * (1.f / (1.f + __expf(-gv.y))));
  float r2 = ov.z * inv * gnw[d0 + 2] * (gv.z * (1.f / (1.f + __expf(-gv.z))));
  float r3 = ov.w * inv * gnw[d0 + 3] * (gv.w * (1.f / (1.f + __expf(-gv.w))));
  bf16x4 o;
  o.x = (__bf16)r0; o.y = (__bf16)r1; o.z = (__bf16)r2; o.w = (__bf16)r3;
  *(bf16x4*)&obf[baseo] = o;
}

// ---------------------------------------------------------------------------
extern "C" void kernel_launch(void* const* d_in, const int* in_sizes, int n_in,
                              void* d_out, int out_size, void* d_ws, size_t ws_size,
                              hipStream_t stream) {
  const float* x = (const float*)d_in[0];
  const float* Wq = (const float*)d_in[1];
  const float* Wk = (const float*)d_in[2];
  const float* Wv = (const float*)d_in[3];
  const float* Wo = (const float*)d_in[4];
  const float* Wg = (const float*)d_in[5];
  const float* Wgk = (const float*)d_in[6];
  const float* Wb = (const float*)d_in[7];
  const float* bb = (const float*)d_in[8];
  const float* A_log = (const float*)d_in[9];
  const float* cqw = (const float*)d_in[10];
  const float* ckw = (const float*)d_in[11];
  const float* cvw = (const float*)d_in[12];
  const float* gnw = (const float*)d_in[13];
  const float* dtb = (const float*)d_in[14];
  float* out = (float*)d_out;

  char* ws = (char*)d_ws;
  __bf16* xbf   = (__bf16*)(ws + 0);            // 8 MB  (later obf)
  __bf16* wq_t  = (__bf16*)(ws + 8388608);      // 2 MB  (later cumbuf)
  __bf16* wk_t  = (__bf16*)(ws + 10485760);
  __bf16* wv_t  = (__bf16*)(ws + 12582912);
  __bf16* wg_t  = (__bf16*)(ws + 14680064);
  __bf16* wo_t  = (__bf16*)(ws + 16777216);
  float* qpre   = (float*)(ws + 18874368);      // 16 MB (later o_pre)
  float* kpre   = (float*)(ws + 35651584);      // 16 MB (later Ubuf)
  float* vpre   = (float*)(ws + 52428800);      // 16 MB (later Wbuf)
  float* gbuf   = (float*)(ws + 69206016);
  float* qhat   = (float*)(ws + 85983232);
  float* khat   = (float*)(ws + 102760448);
  float* vhat   = (float*)(ws + 119537664);     // 16 MB (later Sch)
  float* gk_arr = (float*)(ws + 136314880);     // 256 KB
  float* beta_a = (float*)(ws + 136577024);     // 256 KB
  float* o_pre  = qpre;
  __bf16* obf   = xbf;
  float* cumbuf = (float*)wq_t;   // 256 KB, wq_t dead after big gemm
  float* Ubuf   = kpre;           // kpre dead after conv
  float* Wbuf   = vpre;           // vpre dead after conv
  float* Sch    = vhat;           // vhat dead after chunkA

  k_convert<<<dim3((NM * NC / 4 + 255) / 256), 256, 0, stream>>>(x, xbf, NM * NC / 4);
  dim3 tg(16, 16);
  k_transpose<<<tg, 256, 0, stream>>>(Wq, wq_t);
  k_transpose<<<tg, 256, 0, stream>>>(Wk, wk_t);
  k_transpose<<<tg, 256, 0, stream>>>(Wv, wv_t);
  k_transpose<<<tg, 256, 0, stream>>>(Wg, wg_t);
  k_transpose<<<tg, 256, 0, stream>>>(Wo, wo_t);
  k_gemm<<<dim3(NM / 128, 32), 256, 0, stream>>>(xbf, wq_t, wk_t, wv_t, wg_t,
                                                 qpre, kpre, vpre, gbuf, 8);
  k_projsmall<<<NM, 256, 0, stream>>>(x, Wgk, Wb, bb, A_log, dtb, gk_arr, beta_a);
  k_conv<<<dim3(NT / 64, NB * NH, 3), 256, 0, stream>>>(qpre, kpre, vpre, cqw, ckw,
                                                        cvw, qhat, khat, vhat);
  // chunked gated-delta scan
  k_chunkA<<<1024, 256, 0, stream>>>(khat, vhat, gk_arr, beta_a, cumbuf, Ubuf, Wbuf);
  k_chunkB<<<256, 256, 0, stream>>>(khat, cumbuf, Ubuf, Wbuf, Sch);
  k_out<<<1024, 256, 0, stream>>>(qhat, khat, cumbuf, Ubuf, Wbuf, Sch, o_pre);
  k_gatenorm<<<NM, 256, 0, stream>>>(o_pre, gbuf, gnw, obf);
  k_gemm<<<dim3(NM / 128, 8), 256, 0, stream>>>(obf, wo_t, nullptr, nullptr, nullptr,
                                                out, nullptr, nullptr, nullptr, 8);
}

// Round 6
// 498.992 us; speedup vs baseline: 2.7578x; 1.2256x over previous
//
#include <hip/hip_runtime.h>
#include <math.h>

typedef float f32x4 __attribute__((ext_vector_type(4)));
typedef __bf16 bf16x8 __attribute__((ext_vector_type(8)));
typedef __bf16 bf16x4 __attribute__((ext_vector_type(4)));

// Problem constants
static constexpr int NB = 2, NT = 2048, NC = 1024, NH = 16, ND = 64;
static constexpr int NM = NB * NT;   // 4096 rows

__device__ inline float rdlane(float v, int l) {
  return __builtin_bit_cast(float, __builtin_amdgcn_readlane(__builtin_bit_cast(int, v), l));
}

// ---------------------------------------------------------------------------
// fp32 -> bf16 convert (vectorized x4)
__global__ __launch_bounds__(256) void k_convert(const float* __restrict__ src,
                                                 __bf16* __restrict__ dst, int n4) {
  int i = blockIdx.x * 256 + threadIdx.x;
  if (i >= n4) return;
  float4 v = ((const float4*)src)[i];
  bf16x4 o;
  o.x = (__bf16)v.x; o.y = (__bf16)v.y; o.z = (__bf16)v.z; o.w = (__bf16)v.w;
  ((bf16x4*)dst)[i] = o;
}

// ---------------------------------------------------------------------------
// 1024x1024 fp32 [k][n] -> bf16 [n][k] transpose (LDS-tiled, coalesced)
__global__ __launch_bounds__(256) void k_transpose(const float* __restrict__ src,
                                                   __bf16* __restrict__ dst) {
  __shared__ float t[64][65];
  int r0 = blockIdx.y * 64, c0 = blockIdx.x * 64;
  int lr = threadIdx.x >> 6;   // 0..3
  int lc = threadIdx.x & 63;
#pragma unroll
  for (int j = 0; j < 16; j++) {
    int r = j * 4 + lr;
    t[r][lc] = src[(size_t)(r0 + r) * 1024 + c0 + lc];
  }
  __syncthreads();
#pragma unroll
  for (int j = 0; j < 16; j++) {
    int r = j * 4 + lr;
    dst[(size_t)(c0 + r) * 1024 + r0 + lc] = (__bf16)t[lc][r];
  }
}

// ---------------------------------------------------------------------------
// pack [Wgk|Wb]^T (1024x16 each) into 128x1024 bf16 B-tile; rows 32..127 = 0.
// grid 16 (k-tiles of 64), 256 threads.
__global__ __launch_bounds__(256) void k_buildwgb(const float* __restrict__ Wgk,
    const float* __restrict__ Wb, __bf16* __restrict__ wgb_t) {
  int k0 = blockIdx.x * 64;
  int tid = threadIdx.x;
  int n = tid >> 3;            // 0..31
  int kk = (tid & 7) * 8;      // 0..56
  const float* src = n < 16 ? &Wgk[n] : &Wb[n - 16];
#pragma unroll
  for (int i = 0; i < 8; i++) {
    int k = k0 + kk + i;
    wgb_t[(size_t)n * 1024 + k] = (__bf16)src[(size_t)k * 16];
  }
  // zero rows 32..127 (each block zeroes its slice)
  for (int i = tid; i < 6144; i += 256)
    wgb_t[32 * 1024 + (size_t)blockIdx.x * 6144 + i] = (__bf16)0.f;
}

// ---------------------------------------------------------------------------
// bf16 MFMA GEMM: C[M,N] = A[M,1024] @ B^T (B stored [n][k] bf16), fp32 out.
// sel 0..3: 1024-col outputs (nblkPer blocks each); sel 4: 128-col (ldc 128).
__global__ __launch_bounds__(256) void k_gemm(const __bf16* __restrict__ A,
    const __bf16* B0, const __bf16* B1, const __bf16* B2, const __bf16* B3,
    const __bf16* B4, float* C0, float* C1, float* C2, float* C3, float* C4,
    int nblkPer) {
  constexpr int Kd = 1024;
  int mblk = blockIdx.x;
  int yb = blockIdx.y;
  int sel = yb / nblkPer;
  int nb = yb % nblkPer;
  const __bf16* Bt = sel == 0 ? B0 : sel == 1 ? B1 : sel == 2 ? B2 : sel == 3 ? B3 : B4;
  float* Cp = sel == 0 ? C0 : sel == 1 ? C1 : sel == 2 ? C2 : sel == 3 ? C3 : C4;
  int ldc = sel == 4 ? 128 : 1024;

  __shared__ __bf16 As[128 * 32];
  __shared__ __bf16 Bs[128 * 32];
  int tid = threadIdx.x;
  int lane = tid & 63;
  int w = tid >> 6;
  int wr = w >> 1, wc = w & 1;

  f32x4 acc[4][4];
#pragma unroll
  for (int r = 0; r < 4; r++)
#pragma unroll
    for (int c = 0; c < 4; c++) acc[r][c] = (f32x4){0.f, 0.f, 0.f, 0.f};

  int rowh = tid >> 2;          // 0..63
  int kcol = (tid & 3) * 8;
  const __bf16* aS = A + (size_t)(mblk * 128 + rowh) * Kd + kcol;
  const __bf16* bS = Bt + (size_t)(nb * 128 + rowh) * Kd + kcol;
  int rbase = (wr * 64 + (lane & 15)) * 32 + ((lane >> 4) * 8);
  int cbase = (wc * 64 + (lane & 15)) * 32 + ((lane >> 4) * 8);

  for (int kt = 0; kt < Kd; kt += 32) {
    uint4 a0 = *(const uint4*)(aS + kt);
    uint4 a1 = *(const uint4*)(aS + (size_t)64 * Kd + kt);
    uint4 b0 = *(const uint4*)(bS + kt);
    uint4 b1 = *(const uint4*)(bS + (size_t)64 * Kd + kt);
    __syncthreads();
    *(uint4*)&As[rowh * 32 + kcol] = a0;
    *(uint4*)&As[(rowh + 64) * 32 + kcol] = a1;
    *(uint4*)&Bs[rowh * 32 + kcol] = b0;
    *(uint4*)&Bs[(rowh + 64) * 32 + kcol] = b1;
    __syncthreads();
    bf16x8 af[4], bfr[4];
#pragma unroll
    for (int r = 0; r < 4; r++) af[r] = *(const bf16x8*)&As[rbase + r * 16 * 32];
#pragma unroll
    for (int c = 0; c < 4; c++) bfr[c] = *(const bf16x8*)&Bs[cbase + c * 16 * 32];
#pragma unroll
    for (int r = 0; r < 4; r++)
#pragma unroll
      for (int c = 0; c < 4; c++)
        acc[r][c] = __builtin_amdgcn_mfma_f32_16x16x32_bf16(af[r], bfr[c], acc[r][c], 0, 0, 0);
  }
  int orow = mblk * 128 + wr * 64 + ((lane >> 4) << 2);
  int ocol = nb * 128 + wc * 64 + (lane & 15);
#pragma unroll
  for (int r = 0; r < 4; r++)
#pragma unroll
    for (int c = 0; c < 4; c++)
#pragma unroll
      for (int j = 0; j < 4; j++)
        Cp[(size_t)(orow + r * 16 + j) * ldc + ocol + c * 16] = acc[r][c][j];
}

// ---------------------------------------------------------------------------
// epilogue for gk/beta: pbuf[m][j<32] -> gk_arr/beta_arr [b*16+h][t]
__global__ __launch_bounds__(256) void k_projpost(const float* __restrict__ pbuf,
    const float* __restrict__ bb, const float* __restrict__ A_log,
    const float* __restrict__ dtb, float* __restrict__ gk_arr,
    float* __restrict__ beta_arr) {
  int idx = blockIdx.x * 256 + threadIdx.x;   // 4096*32
  int m = idx >> 5, j = idx & 31;
  int b = m >> 11, t = m & 2047;
  float v = pbuf[(size_t)m * 128 + j];
  if (j < 16) {
    float z = v + dtb[j];
    float sp = z > 20.f ? z : log1pf(__expf(z));
    gk_arr[((size_t)(b * 16 + j)) * 2048 + t] = -__expf(A_log[j]) * sp;
  } else {
    int jj = j - 16;
    float z = v + bb[jj];
    beta_arr[((size_t)(b * 16 + jj)) * 2048 + t] = 1.f / (1.f + __expf(-z));
  }
}

// ---------------------------------------------------------------------------
// depthwise causal conv(K=4) + silu; for q,k additionally l2norm + rope(32).
__global__ __launch_bounds__(256) void k_conv(
    const float* __restrict__ qpre, const float* __restrict__ kpre,
    const float* __restrict__ vpre, const float* __restrict__ cqw,
    const float* __restrict__ ckw, const float* __restrict__ cvw,
    float* __restrict__ qhat, float* __restrict__ khat, float* __restrict__ vhat) {
  int z = blockIdx.z;
  const float* src = z == 0 ? qpre : z == 1 ? kpre : vpre;
  const float* cw = z == 0 ? cqw : z == 1 ? ckw : cvw;
  float* dst = z == 0 ? qhat : z == 1 ? khat : vhat;
  int t0 = blockIdx.x * 64;
  int bh = blockIdx.y;
  int b = bh >> 4, h = bh & 15;
  int tid = threadIdx.x;
  __shared__ float tile[67 * 64];
  __shared__ float outb[64 * 64];
  for (int i = tid; i < 67 * 64; i += 256) {
    int r = i >> 6, c = i & 63;
    int t = t0 - 3 + r;
    tile[i] = (t >= 0) ? src[((size_t)(b * 2048 + t)) * 1024 + h * 64 + c] : 0.f;
  }
  __syncthreads();
  int c = tid & 63;
  int rb = (tid >> 6) * 16;
  float4 w4 = *(const float4*)&cw[(h * 64 + c) * 4];
  size_t obase = ((size_t)bh) * 2048 * 64;
#pragma unroll
  for (int rr = 0; rr < 16; rr++) {
    int r = rb + rr;
    float y = tile[r * 64 + c] * w4.x + tile[(r + 1) * 64 + c] * w4.y +
              tile[(r + 2) * 64 + c] * w4.z + tile[(r + 3) * 64 + c] * w4.w;
    float sv = y * (1.f / (1.f + __expf(-y)));
    if (z == 2) dst[obase + (size_t)(t0 + r) * 64 + c] = sv;
    else outb[r * 64 + c] = sv;
  }
  if (z == 2) return;
  __syncthreads();
  int r = tid >> 2;
  int p = tid & 3;
  float ss = 0.f;
#pragma unroll
  for (int i2 = 0; i2 < 16; i2++) { float vv = outb[r * 64 + p * 16 + i2]; ss += vv * vv; }
  ss += __shfl_xor(ss, 1);
  ss += __shfl_xor(ss, 2);
  float inv = rsqrtf(ss + 1e-6f);
  int tg = t0 + r;
#pragma unroll
  for (int i2 = 0; i2 < 16; i2++) {
    int cc = p * 16 + i2;
    float val = outb[r * 64 + cc] * inv;
    float res;
    if (cc < 16) {
      float x2 = outb[r * 64 + cc + 16] * inv;
      float ang = tg * __expf(-0.5756462732485114f * cc);   // ln(1e4)/16
      float sn, cn; sincosf(ang, &sn, &cn);
      res = val * cn - x2 * sn;
    } else if (cc < 32) {
      float x1 = outb[r * 64 + cc - 16] * inv;
      float ang = tg * __expf(-0.5756462732485114f * (cc - 16));
      float sn, cn; sincosf(ang, &sn, &cn);
      res = val * cn + x1 * sn;
    } else res = val;
    dst[obase + (size_t)tg * 64 + cc] = res;
  }
}

// ---------------------------------------------------------------------------
// Chunked gated-delta, Phase A v2 (parallel, 1024 blocks = bh*32+ch):
//   cum = inclusive cumsum(g) via wave shfl-scan
//   M[t][s] = b_t exp(cum_t-cum_s) (k_t.k_s), s<t  -- K.K^T via bf16 MFMA
//   Solve (I+M)[U|W] = [diag(b)V | diag(b*Gamma)K] -- per-thread-column
//   forward substitution in registers (M rows read as broadcast float4)
__global__ __launch_bounds__(256) void k_chunkA(
    const float* __restrict__ khat, const float* __restrict__ vhat,
    const float* __restrict__ gk_arr, const float* __restrict__ beta_arr,
    float* __restrict__ cumbuf, float* __restrict__ Ubuf, float* __restrict__ Wbuf) {
  int bid = blockIdx.x;
  int bh = bid >> 5, ch = bid & 31;
  int tid = threadIdx.x;
  int lane = tid & 63, w = tid >> 6;
  __shared__ __bf16 Kbf[64 * 64];                         // 8 KB, chunk-swizzled
  __shared__ __attribute__((aligned(16))) float Msh[64 * 68];  // 17.4 KB
  __shared__ float cumsh[64], bsh[64];
  size_t kbase = (size_t)bh * (2048 * 64) + (size_t)ch * 4096;
  size_t gb = (size_t)bh * 2048 + ch * 64;
  size_t cb4096 = (size_t)(bh * 32 + ch) * 4096;

  // --- stage K as bf16, XOR-swizzled (chunk ^= row&7) to kill 128B-row conflicts
  {
    int row = tid >> 2, c16 = (tid & 3) * 16;
    const float* src = &khat[kbase + row * 64 + c16];
    float4 f0 = *(const float4*)(src + 0);
    float4 f1 = *(const float4*)(src + 4);
    float4 f2 = *(const float4*)(src + 8);
    float4 f3 = *(const float4*)(src + 12);
    bf16x8 h0, h1;
    h0[0] = (__bf16)f0.x; h0[1] = (__bf16)f0.y; h0[2] = (__bf16)f0.z; h0[3] = (__bf16)f0.w;
    h0[4] = (__bf16)f1.x; h0[5] = (__bf16)f1.y; h0[6] = (__bf16)f1.z; h0[7] = (__bf16)f1.w;
    h1[0] = (__bf16)f2.x; h1[1] = (__bf16)f2.y; h1[2] = (__bf16)f2.z; h1[3] = (__bf16)f2.w;
    h1[4] = (__bf16)f3.x; h1[5] = (__bf16)f3.y; h1[6] = (__bf16)f3.z; h1[7] = (__bf16)f3.w;
    int ch0 = ((c16 >> 3) + 0) ^ (row & 7);
    int ch1 = ((c16 >> 3) + 1) ^ (row & 7);
    *(bf16x8*)&Kbf[row * 64 + ch0 * 8] = h0;
    *(bf16x8*)&Kbf[row * 64 + ch1 * 8] = h1;
  }
  // --- zero Msh (so substitution can over-read float4 chunks safely)
  for (int i = tid; i < 64 * 68; i += 256) Msh[i] = 0.f;
  // --- g/beta load + wave-parallel inclusive scan (wave 0 only)
  if (tid < 64) {
    float g = gk_arr[gb + tid];
    float bv = beta_arr[gb + tid];
#pragma unroll
    for (int d = 1; d < 64; d <<= 1) {
      float n = __shfl_up(g, d, 64);
      if (tid >= d) g += n;
    }
    cumsh[tid] = g;
    bsh[tid] = bv;
    cumbuf[(size_t)(bh * 32 + ch) * 64 + tid] = g;
  }
  __syncthreads();

  // --- M = tril(K K^T) scaled, via MFMA. wave w owns rows 16w..16w+15.
  {
    f32x4 macc[4];
#pragma unroll
    for (int c = 0; c < 4; c++) macc[c] = (f32x4){0.f, 0.f, 0.f, 0.f};
    int arow = w * 16 + (lane & 15);
    int kb = lane >> 4;
    bf16x8 af0 = *(const bf16x8*)&Kbf[arow * 64 + ((0 + kb) ^ (arow & 7)) * 8];
    bf16x8 af1 = *(const bf16x8*)&Kbf[arow * 64 + ((4 + kb) ^ (arow & 7)) * 8];
#pragma unroll
    for (int c = 0; c < 4; c++) {
      if (c <= w) {
        int brow = c * 16 + (lane & 15);
        bf16x8 bf0 = *(const bf16x8*)&Kbf[brow * 64 + ((0 + kb) ^ (brow & 7)) * 8];
        bf16x8 bf1 = *(const bf16x8*)&Kbf[brow * 64 + ((4 + kb) ^ (brow & 7)) * 8];
        macc[c] = __builtin_amdgcn_mfma_f32_16x16x32_bf16(af0, bf0, macc[c], 0, 0, 0);
        macc[c] = __builtin_amdgcn_mfma_f32_16x16x32_bf16(af1, bf1, macc[c], 0, 0, 0);
      }
    }
    // scale + write lower tiles
    float bt[4], ct[4];
#pragma unroll
    for (int j = 0; j < 4; j++) {
      int trow = w * 16 + (lane >> 4) * 4 + j;
      bt[j] = bsh[trow];
      ct[j] = cumsh[trow];
    }
#pragma unroll
    for (int c = 0; c < 4; c++) {
      if (c <= w) {
        int scol = c * 16 + (lane & 15);
        float cums = cumsh[scol];
#pragma unroll
        for (int j = 0; j < 4; j++) {
          int trow = w * 16 + (lane >> 4) * 4 + j;
          float val = macc[c][j] * bt[j] * __expf(ct[j] - cums);
          Msh[trow * 68 + scol] = (scol < trow) ? val : 0.f;
        }
      }
    }
  }

  // --- RHS columns into registers (threads 0..127: c<64 -> U col, else W col)
  float uw[64];
  int c = tid;
  if (tid < 128) {
    bool isU = c < 64;
    int cc = c & 63;
    const float* src = isU ? &vhat[kbase + cc] : &khat[kbase + cc];
#pragma unroll
    for (int t = 0; t < 64; t++) {
      float r = src[t * 64] * bsh[t];
      if (!isU) r *= __expf(cumsh[t]);
      uw[t] = r;
    }
  }
  __syncthreads();   // Msh ready

  if (tid < 128) {
    // forward substitution, fully in registers; M row chunks broadcast
#pragma unroll
    for (int t = 1; t < 64; t++) {
      float acc = 0.f;
#pragma unroll
      for (int q = 0; q <= (t - 1) >> 2; q++) {
        float4 m4 = *(const float4*)&Msh[t * 68 + q * 4];
        acc += m4.x * uw[q * 4 + 0] + m4.y * uw[q * 4 + 1] +
               m4.z * uw[q * 4 + 2] + m4.w * uw[q * 4 + 3];
      }
      uw[t] -= acc;
    }
    bool isU = c < 64;
    int cc = c & 63;
    float* dst = isU ? &Ubuf[cb4096 + cc] : &Wbuf[cb4096 + cc];
#pragma unroll
    for (int t = 0; t < 64; t++) dst[t * 64] = uw[t];
  }
}

// ---------------------------------------------------------------------------
// Phase B (sequential over chunks): grid 256 = bh*8 + vblock(8 cols).
// S in REGISTERS: lane l of wave q holds S[l][c0..c0+1], c0 = vb*8 + q*2.
__global__ __launch_bounds__(256) void k_chunkB(
    const float* __restrict__ khat, const float* __restrict__ cumbuf,
    const float* __restrict__ Ubuf, const float* __restrict__ Wbuf,
    float* __restrict__ Sch) {
  int bid = blockIdx.x;
  int bh = bid >> 3, vb = bid & 7;
  int tid = threadIdx.x;
  int lane = tid & 63, q_ = tid >> 6;
  int c0 = vb * 8 + q_ * 2;
  __shared__ float Ksh[64 * 68];
  float S0 = 0.f, S1 = 0.f;
  for (int ch = 0; ch < 32; ch++) {
    size_t cb = (size_t)(bh * 32 + ch);
    size_t kbase = (size_t)bh * (2048 * 64) + (size_t)ch * 4096;
    __syncthreads();   // previous update done reading Ksh
#pragma unroll
    for (int n4 = 0; n4 < 4; n4++) {
      int n = tid + n4 * 256;              // 0..1023 float4s
      float4 kv = *(const float4*)&khat[kbase + (size_t)n * 4];
      int row = n >> 4, col = (n & 15) * 4;
      *(float4*)&Ksh[row * 68 + col] = kv;
    }
    float cumv = cumbuf[cb * 64 + lane];
    float cum63 = rdlane(cumv, 63);
    float sc = __expf(cum63 - cumv);
    float Gend = __expf(cum63);
    float2 uv = *(const float2*)&Ubuf[cb * 4096 + (size_t)lane * 64 + c0];
    float Wrow[64];
#pragma unroll
    for (int i4 = 0; i4 < 16; i4++) {
      float4 wv = *(const float4*)&Wbuf[cb * 4096 + (size_t)lane * 64 + i4 * 4];
      Wrow[i4 * 4 + 0] = wv.x; Wrow[i4 * 4 + 1] = wv.y;
      Wrow[i4 * 4 + 2] = wv.z; Wrow[i4 * 4 + 3] = wv.w;
    }
    Sch[cb * 4096 + (size_t)(c0 + 0) * 64 + lane] = S0;
    Sch[cb * 4096 + (size_t)(c0 + 1) * 64 + lane] = S1;
    float a0 = 0.f, a1 = 0.f;
#pragma unroll
    for (int i = 0; i < 64; i++) {
      float s0 = rdlane(S0, i), s1 = rdlane(S1, i);
      a0 += Wrow[i] * s0;
      a1 += Wrow[i] * s1;
    }
    float D0 = sc * (uv.x - a0);
    float D1 = sc * (uv.y - a1);
    __syncthreads();   // Ksh staged
    float n0 = 0.f, n1 = 0.f;
#pragma unroll
    for (int t = 0; t < 64; t++) {
      float d0 = rdlane(D0, t), d1 = rdlane(D1, t);
      float kk = Ksh[t * 68 + lane];
      n0 += kk * d0;
      n1 += kk * d1;
    }
    S0 = Gend * S0 + n0;
    S1 = Gend * S1 + n1;
  }
}

// Phase C (parallel, 1024 blocks): O = diag(G) Q S_in + (QK^T . decaymask) Delta
__global__ __launch_bounds__(256) void k_out(
    const float* __restrict__ qhat, const float* __restrict__ khat,
    const float* __restrict__ cumbuf, const float* __restrict__ Ubuf,
    const float* __restrict__ Wbuf, const float* __restrict__ Sch,
    float* __restrict__ o_pre) {
  int bid = blockIdx.x;
  int bh = bid >> 5, ch = bid & 31;
  int b = bh >> 4, h = bh & 15;
  int tid = threadIdx.x;
  __shared__ float B1[64][65];  // W -> Q -> P
  __shared__ float B2[64][65];  // S -> K
  __shared__ float B3[64][65];  // Delta
  __shared__ float cumsh[64];
  size_t cb = (size_t)(bh * 32 + ch);
  size_t kbase = (size_t)bh * (2048 * 64) + (size_t)ch * 4096;
  if (tid < 64) cumsh[tid] = cumbuf[cb * 64 + tid];
  for (int idx = tid; idx < 4096; idx += 256) {
    B1[idx >> 6][idx & 63] = Wbuf[cb * 4096 + idx];
    B2[idx & 63][idx >> 6] = Sch[cb * 4096 + idx];   // Sch is column-major
  }
  __syncthreads();
  int t_ = tid & 63, q_ = tid >> 6;   // q_ 0..3 -> 16 cols each
  int c0 = q_ * 16;
  float acc[16], o1[16], p[16];
  // Delta = U - W S  -> B3
#pragma unroll
  for (int j = 0; j < 16; j++) acc[j] = 0.f;
  for (int i = 0; i < 64; i++) {
    float w = B1[t_][i];
#pragma unroll
    for (int j = 0; j < 16; j++) acc[j] += w * B2[i][c0 + j];
  }
#pragma unroll
  for (int j = 0; j < 16; j += 4) {
    float4 u = *(const float4*)&Ubuf[cb * 4096 + (size_t)t_ * 64 + c0 + j];
    B3[t_][c0 + j + 0] = u.x - acc[j + 0];
    B3[t_][c0 + j + 1] = u.y - acc[j + 1];
    B3[t_][c0 + j + 2] = u.z - acc[j + 2];
    B3[t_][c0 + j + 3] = u.w - acc[j + 3];
  }
  __syncthreads();
  // B1 <- Q
  for (int idx = tid; idx < 4096; idx += 256)
    B1[idx >> 6][idx & 63] = qhat[kbase + idx];
  __syncthreads();
  // O1 = Gt * (Q S)
#pragma unroll
  for (int j = 0; j < 16; j++) o1[j] = 0.f;
  for (int i = 0; i < 64; i++) {
    float qv = B1[t_][i];
#pragma unroll
    for (int j = 0; j < 16; j++) o1[j] += qv * B2[i][c0 + j];
  }
  {
    float Gt = __expf(cumsh[t_]);
#pragma unroll
    for (int j = 0; j < 16; j++) o1[j] *= Gt;
  }
  __syncthreads();
  // B2 <- K
  for (int idx = tid; idx < 4096; idx += 256)
    B2[idx >> 6][idx & 63] = khat[kbase + idx];
  __syncthreads();
  // P[t][s] = (q_t.k_s) exp(cum_t-cum_s), s<=t
#pragma unroll
  for (int m = 0; m < 16; m++) {
    int s = c0 + m;
    float d = 0.f;
    if (s <= t_) {
      for (int i = 0; i < 64; i++) d += B1[t_][i] * B2[s][i];
      d *= __expf(cumsh[t_] - cumsh[s]);
    }
    p[m] = d;
  }
  __syncthreads();
#pragma unroll
  for (int m = 0; m < 16; m++) B1[t_][c0 + m] = p[m];
  __syncthreads();
  // O = O1 + P Delta
  for (int s = 0; s < 64; s++) {
    float pv = B1[t_][s];
#pragma unroll
    for (int j = 0; j < 16; j++) o1[j] += pv * B3[s][c0 + j];
  }
  size_t ob = ((size_t)(b * 2048 + ch * 64 + t_)) * 1024 + h * 64 + c0;
#pragma unroll
  for (int j = 0; j < 16; j += 4) {
    float4 o4 = {o1[j], o1[j + 1], o1[j + 2], o1[j + 3]};
    *(float4*)&o_pre[ob + j] = o4;
  }
}

// ---------------------------------------------------------------------------
// epilogue: per-(m,h) RMSNorm(64, eps 1e-5, mean) * gnorm_w * silu(g) -> bf16
__global__ __launch_bounds__(256) void k_gatenorm(const float* __restrict__ o_pre,
    const float* __restrict__ g, const float* __restrict__ gnw,
    __bf16* __restrict__ obf) {
  int m = blockIdx.x;
  int tid = threadIdx.x;
  size_t baseo = (size_t)m * 1024 + tid * 4;
  float4 ov = *(const float4*)&o_pre[baseo];
  float ss = ov.x * ov.x + ov.y * ov.y + ov.z * ov.z + ov.w * ov.w;
  ss += __shfl_xor(ss, 1);
  ss += __shfl_xor(ss, 2);
  ss += __shfl_xor(ss, 4);
  ss += __shfl_xor(ss, 8);
  float inv = rsqrtf(ss * (1.f / 64.f) + 1e-5f);
  float4 gv = *(const float4*)&g[baseo];
  int d0 = (tid & 15) * 4;
  float r0 = ov.x * inv * gnw[d0 + 0] * (gv.x * (1.f / (1.f + __expf(-gv.x))));
  float r1 = ov.y * inv * gnw[d0 + 1] * (gv.y * (1.f / (1.f + __expf(-gv.y))));
  float r2 = ov.z * inv * gnw[d0 + 2] * (gv.z * (1.f / (1.f + __expf(-gv.z))));
  float r3 = ov.w * inv * gnw[d0 + 3] * (gv.w * (1.f / (1.f + __expf(-gv.w))));
  bf16x4 o;
  o.x = (__bf16)r0; o.y = (__bf16)r1; o.z = (__bf16)r2; o.w = (__bf16)r3;
  *(bf16x4*)&obf[baseo] = o;
}

// ---------------------------------------------------------------------------
extern "C" void kernel_launch(void* const* d_in, const int* in_sizes, int n_in,
                              void* d_out, int out_size, void* d_ws, size_t ws_size,
                              hipStream_t stream) {
  const float* x = (const float*)d_in[0];
  const float* Wq = (const float*)d_in[1];
  const float* Wk = (const float*)d_in[2];
  const float* Wv = (const float*)d_in[3];
  const float* Wo = (const float*)d_in[4];
  const float* Wg = (const float*)d_in[5];
  const float* Wgk = (const float*)d_in[6];
  const float* Wb = (const float*)d_in[7];
  const float* bb = (const float*)d_in[8];
  const float* A_log = (const float*)d_in[9];
  const float* cqw = (const float*)d_in[10];
  const float* ckw = (const float*)d_in[11];
  const float* cvw = (const float*)d_in[12];
  const float* gnw = (const float*)d_in[13];
  const float* dtb = (const float*)d_in[14];
  float* out = (float*)d_out;

  char* ws = (char*)d_ws;
  __bf16* xbf   = (__bf16*)(ws + 0);            // 8 MB  (later obf)
  __bf16* wq_t  = (__bf16*)(ws + 8388608);      // 2 MB  (later cumbuf)
  __bf16* wk_t  = (__bf16*)(ws + 10485760);
  __bf16* wv_t  = (__bf16*)(ws + 12582912);
  __bf16* wg_t  = (__bf16*)(ws + 14680064);
  __bf16* wo_t  = (__bf16*)(ws + 16777216);
  float* qpre   = (float*)(ws + 18874368);      // 16 MB (later o_pre)
  float* kpre   = (float*)(ws + 35651584);      // 16 MB (later Ubuf)
  float* vpre   = (float*)(ws + 52428800);      // 16 MB (later Wbuf)
  float* gbuf   = (float*)(ws + 69206016);
  float* qhat   = (float*)(ws + 85983232);
  float* khat   = (float*)(ws + 102760448);
  float* vhat   = (float*)(ws + 119537664);     // 16 MB (later Sch)
  float* gk_arr = (float*)(ws + 136314880);     // 256 KB
  float* beta_a = (float*)(ws + 136577024);     // 256 KB
  float* o_pre  = qpre;
  __bf16* obf   = xbf;
  float* cumbuf = (float*)wq_t;   // 256 KB, wq_t dead after big gemm
  float* Ubuf   = kpre;           // kpre dead after conv
  float* Wbuf   = vpre;           // vpre dead after conv
  float* Sch    = vhat;           // vhat dead after chunkA
  // gk/beta projection staging — both live only between gemm and conv:
  __bf16* wgb_t = (__bf16*)khat;  // 256 KB in khat region (conv writes after)
  float* pbuf   = qhat;           // 2 MB in qhat region   (conv writes after)

  k_convert<<<dim3((NM * NC / 4 + 255) / 256), 256, 0, stream>>>(x, xbf, NM * NC / 4);
  dim3 tg(16, 16);
  k_transpose<<<tg, 256, 0, stream>>>(Wq, wq_t);
  k_transpose<<<tg, 256, 0, stream>>>(Wk, wk_t);
  k_transpose<<<tg, 256, 0, stream>>>(Wv, wv_t);
  k_transpose<<<tg, 256, 0, stream>>>(Wg, wg_t);
  k_transpose<<<tg, 256, 0, stream>>>(Wo, wo_t);
  k_buildwgb<<<16, 256, 0, stream>>>(Wgk, Wb, wgb_t);
  // fused q/k/v/g + gk/beta projections (grid.y = 4*8 + 1)
  k_gemm<<<dim3(NM / 128, 33), 256, 0, stream>>>(xbf, wq_t, wk_t, wv_t, wg_t, wgb_t,
                                                 qpre, kpre, vpre, gbuf, pbuf, 8);
  k_projpost<<<NM * 32 / 256, 256, 0, stream>>>(pbuf, bb, A_log, dtb, gk_arr, beta_a);
  k_conv<<<dim3(NT / 64, NB * NH, 3), 256, 0, stream>>>(qpre, kpre, vpre, cqw, ckw,
                                                        cvw, qhat, khat, vhat);
  // chunked gated-delta scan
  k_chunkA<<<1024, 256, 0, stream>>>(khat, vhat, gk_arr, beta_a, cumbuf, Ubuf, Wbuf);
  k_chunkB<<<256, 256, 0, stream>>>(khat, cumbuf, Ubuf, Wbuf, Sch);
  k_out<<<1024, 256, 0, stream>>>(qhat, khat, cumbuf, Ubuf, Wbuf, Sch, o_pre);
  k_gatenorm<<<NM, 256, 0, stream>>>(o_pre, gbuf, gnw, obf);
  k_gemm<<<dim3(NM / 128, 8), 256, 0, stream>>>(obf, wo_t, nullptr, nullptr, nullptr,
                                                nullptr, out, nullptr, nullptr, nullptr,
                                                nullptr, 8);
}

// Round 7
// 473.744 us; speedup vs baseline: 2.9047x; 1.0533x over previous
//
#include <hip/hip_runtime.h>
#include <math.h>

typedef float f32x4 __attribute__((ext_vector_type(4)));
typedef __bf16 bf16x8 __attribute__((ext_vector_type(8)));
typedef __bf16 bf16x4 __attribute__((ext_vector_type(4)));

// Problem constants
static constexpr int NB = 2, NT = 2048, NC = 1024, NH = 16, ND = 64;
static constexpr int NM = NB * NT;   // 4096 rows

__device__ inline float rdlane(float v, int l) {
  return __builtin_bit_cast(float, __builtin_amdgcn_readlane(__builtin_bit_cast(int, v), l));
}

// ---------------------------------------------------------------------------
// fp32 -> bf16 convert (vectorized x4)
__global__ __launch_bounds__(256) void k_convert(const float* __restrict__ src,
                                                 __bf16* __restrict__ dst, int n4) {
  int i = blockIdx.x * 256 + threadIdx.x;
  if (i >= n4) return;
  float4 v = ((const float4*)src)[i];
  bf16x4 o;
  o.x = (__bf16)v.x; o.y = (__bf16)v.y; o.z = (__bf16)v.z; o.w = (__bf16)v.w;
  ((bf16x4*)dst)[i] = o;
}

// ---------------------------------------------------------------------------
// 1024x1024 fp32 [k][n] -> bf16 [n][k] transpose (LDS-tiled, coalesced)
__global__ __launch_bounds__(256) void k_transpose(const float* __restrict__ src,
                                                   __bf16* __restrict__ dst) {
  __shared__ float t[64][65];
  int r0 = blockIdx.y * 64, c0 = blockIdx.x * 64;
  int lr = threadIdx.x >> 6;   // 0..3
  int lc = threadIdx.x & 63;
#pragma unroll
  for (int j = 0; j < 16; j++) {
    int r = j * 4 + lr;
    t[r][lc] = src[(size_t)(r0 + r) * 1024 + c0 + lc];
  }
  __syncthreads();
#pragma unroll
  for (int j = 0; j < 16; j++) {
    int r = j * 4 + lr;
    dst[(size_t)(c0 + r) * 1024 + r0 + lc] = (__bf16)t[lc][r];
  }
}

// ---------------------------------------------------------------------------
// pack [Wgk|Wb]^T (1024x16 each) into 128x1024 bf16 B-tile; rows 32..127 = 0.
// grid 16 (k-tiles of 64), 256 threads.
__global__ __launch_bounds__(256) void k_buildwgb(const float* __restrict__ Wgk,
    const float* __restrict__ Wb, __bf16* __restrict__ wgb_t) {
  int k0 = blockIdx.x * 64;
  int tid = threadIdx.x;
  int n = tid >> 3;            // 0..31
  int kk = (tid & 7) * 8;      // 0..56
  const float* src = n < 16 ? &Wgk[n] : &Wb[n - 16];
#pragma unroll
  for (int i = 0; i < 8; i++) {
    int k = k0 + kk + i;
    wgb_t[(size_t)n * 1024 + k] = (__bf16)src[(size_t)k * 16];
  }
  // zero rows 32..127 (each block zeroes its slice)
  for (int i = tid; i < 6144; i += 256)
    wgb_t[32 * 1024 + (size_t)blockIdx.x * 6144 + i] = (__bf16)0.f;
}

// ---------------------------------------------------------------------------
// bf16 MFMA GEMM: C[M,N] = A[M,1024] @ B^T (B stored [n][k] bf16), fp32 out.
// sel 0..3: 1024-col outputs (nblkPer blocks each); sel 4: 128-col (ldc 128).
__global__ __launch_bounds__(256) void k_gemm(const __bf16* __restrict__ A,
    const __bf16* B0, const __bf16* B1, const __bf16* B2, const __bf16* B3,
    const __bf16* B4, float* C0, float* C1, float* C2, float* C3, float* C4,
    int nblkPer) {
  constexpr int Kd = 1024;
  int mblk = blockIdx.x;
  int yb = blockIdx.y;
  int sel = yb / nblkPer;
  int nb = yb % nblkPer;
  const __bf16* Bt = sel == 0 ? B0 : sel == 1 ? B1 : sel == 2 ? B2 : sel == 3 ? B3 : B4;
  float* Cp = sel == 0 ? C0 : sel == 1 ? C1 : sel == 2 ? C2 : sel == 3 ? C3 : C4;
  int ldc = sel == 4 ? 128 : 1024;

  __shared__ __bf16 As[128 * 32];
  __shared__ __bf16 Bs[128 * 32];
  int tid = threadIdx.x;
  int lane = tid & 63;
  int w = tid >> 6;
  int wr = w >> 1, wc = w & 1;

  f32x4 acc[4][4];
#pragma unroll
  for (int r = 0; r < 4; r++)
#pragma unroll
    for (int c = 0; c < 4; c++) acc[r][c] = (f32x4){0.f, 0.f, 0.f, 0.f};

  int rowh = tid >> 2;          // 0..63
  int kcol = (tid & 3) * 8;
  const __bf16* aS = A + (size_t)(mblk * 128 + rowh) * Kd + kcol;
  const __bf16* bS = Bt + (size_t)(nb * 128 + rowh) * Kd + kcol;
  int rbase = (wr * 64 + (lane & 15)) * 32 + ((lane >> 4) * 8);
  int cbase = (wc * 64 + (lane & 15)) * 32 + ((lane >> 4) * 8);

  for (int kt = 0; kt < Kd; kt += 32) {
    uint4 a0 = *(const uint4*)(aS + kt);
    uint4 a1 = *(const uint4*)(aS + (size_t)64 * Kd + kt);
    uint4 b0 = *(const uint4*)(bS + kt);
    uint4 b1 = *(const uint4*)(bS + (size_t)64 * Kd + kt);
    __syncthreads();
    *(uint4*)&As[rowh * 32 + kcol] = a0;
    *(uint4*)&As[(rowh + 64) * 32 + kcol] = a1;
    *(uint4*)&Bs[rowh * 32 + kcol] = b0;
    *(uint4*)&Bs[(rowh + 64) * 32 + kcol] = b1;
    __syncthreads();
    bf16x8 af[4], bfr[4];
#pragma unroll
    for (int r = 0; r < 4; r++) af[r] = *(const bf16x8*)&As[rbase + r * 16 * 32];
#pragma unroll
    for (int c = 0; c < 4; c++) bfr[c] = *(const bf16x8*)&Bs[cbase + c * 16 * 32];
#pragma unroll
    for (int r = 0; r < 4; r++)
#pragma unroll
      for (int c = 0; c < 4; c++)
        acc[r][c] = __builtin_amdgcn_mfma_f32_16x16x32_bf16(af[r], bfr[c], acc[r][c], 0, 0, 0);
  }
  int orow = mblk * 128 + wr * 64 + ((lane >> 4) << 2);
  int ocol = nb * 128 + wc * 64 + (lane & 15);
#pragma unroll
  for (int r = 0; r < 4; r++)
#pragma unroll
    for (int c = 0; c < 4; c++)
#pragma unroll
      for (int j = 0; j < 4; j++)
        Cp[(size_t)(orow + r * 16 + j) * ldc + ocol + c * 16] = acc[r][c][j];
}

// ---------------------------------------------------------------------------
// epilogue for gk/beta: pbuf[m][j<32] -> gk_arr/beta_arr [b*16+h][t]
__global__ __launch_bounds__(256) void k_projpost(const float* __restrict__ pbuf,
    const float* __restrict__ bb, const float* __restrict__ A_log,
    const float* __restrict__ dtb, float* __restrict__ gk_arr,
    float* __restrict__ beta_arr) {
  int idx = blockIdx.x * 256 + threadIdx.x;   // 4096*32
  int m = idx >> 5, j = idx & 31;
  int b = m >> 11, t = m & 2047;
  float v = pbuf[(size_t)m * 128 + j];
  if (j < 16) {
    float z = v + dtb[j];
    float sp = z > 20.f ? z : log1pf(__expf(z));
    gk_arr[((size_t)(b * 16 + j)) * 2048 + t] = -__expf(A_log[j]) * sp;
  } else {
    int jj = j - 16;
    float z = v + bb[jj];
    beta_arr[((size_t)(b * 16 + jj)) * 2048 + t] = 1.f / (1.f + __expf(-z));
  }
}

// ---------------------------------------------------------------------------
// depthwise causal conv(K=4) + silu; for q,k additionally l2norm + rope(32).
__global__ __launch_bounds__(256) void k_conv(
    const float* __restrict__ qpre, const float* __restrict__ kpre,
    const float* __restrict__ vpre, const float* __restrict__ cqw,
    const float* __restrict__ ckw, const float* __restrict__ cvw,
    float* __restrict__ qhat, float* __restrict__ khat, float* __restrict__ vhat) {
  int z = blockIdx.z;
  const float* src = z == 0 ? qpre : z == 1 ? kpre : vpre;
  const float* cw = z == 0 ? cqw : z == 1 ? ckw : cvw;
  float* dst = z == 0 ? qhat : z == 1 ? khat : vhat;
  int t0 = blockIdx.x * 64;
  int bh = blockIdx.y;
  int b = bh >> 4, h = bh & 15;
  int tid = threadIdx.x;
  __shared__ float tile[67 * 64];
  __shared__ float outb[64 * 64];
  for (int i = tid; i < 67 * 64; i += 256) {
    int r = i >> 6, c = i & 63;
    int t = t0 - 3 + r;
    tile[i] = (t >= 0) ? src[((size_t)(b * 2048 + t)) * 1024 + h * 64 + c] : 0.f;
  }
  __syncthreads();
  int c = tid & 63;
  int rb = (tid >> 6) * 16;
  float4 w4 = *(const float4*)&cw[(h * 64 + c) * 4];
  size_t obase = ((size_t)bh) * 2048 * 64;
#pragma unroll
  for (int rr = 0; rr < 16; rr++) {
    int r = rb + rr;
    float y = tile[r * 64 + c] * w4.x + tile[(r + 1) * 64 + c] * w4.y +
              tile[(r + 2) * 64 + c] * w4.z + tile[(r + 3) * 64 + c] * w4.w;
    float sv = y * (1.f / (1.f + __expf(-y)));
    if (z == 2) dst[obase + (size_t)(t0 + r) * 64 + c] = sv;
    else outb[r * 64 + c] = sv;
  }
  if (z == 2) return;
  __syncthreads();
  int r = tid >> 2;
  int p = tid & 3;
  float ss = 0.f;
#pragma unroll
  for (int i2 = 0; i2 < 16; i2++) { float vv = outb[r * 64 + p * 16 + i2]; ss += vv * vv; }
  ss += __shfl_xor(ss, 1);
  ss += __shfl_xor(ss, 2);
  float inv = rsqrtf(ss + 1e-6f);
  int tg = t0 + r;
#pragma unroll
  for (int i2 = 0; i2 < 16; i2++) {
    int cc = p * 16 + i2;
    float val = outb[r * 64 + cc] * inv;
    float res;
    if (cc < 16) {
      float x2 = outb[r * 64 + cc + 16] * inv;
      float ang = tg * __expf(-0.5756462732485114f * cc);   // ln(1e4)/16
      float sn, cn; sincosf(ang, &sn, &cn);
      res = val * cn - x2 * sn;
    } else if (cc < 32) {
      float x1 = outb[r * 64 + cc - 16] * inv;
      float ang = tg * __expf(-0.5756462732485114f * (cc - 16));
      float sn, cn; sincosf(ang, &sn, &cn);
      res = val * cn + x1 * sn;
    } else res = val;
    dst[obase + (size_t)tg * 64 + cc] = res;
  }
}

// ---------------------------------------------------------------------------
// Chunked gated-delta, Phase A v2 (parallel, 1024 blocks = bh*32+ch)
__global__ __launch_bounds__(256) void k_chunkA(
    const float* __restrict__ khat, const float* __restrict__ vhat,
    const float* __restrict__ gk_arr, const float* __restrict__ beta_arr,
    float* __restrict__ cumbuf, float* __restrict__ Ubuf, float* __restrict__ Wbuf) {
  int bid = blockIdx.x;
  int bh = bid >> 5, ch = bid & 31;
  int tid = threadIdx.x;
  int lane = tid & 63, w = tid >> 6;
  __shared__ __bf16 Kbf[64 * 64];                         // 8 KB, chunk-swizzled
  __shared__ __attribute__((aligned(16))) float Msh[64 * 68];  // 17.4 KB
  __shared__ float cumsh[64], bsh[64];
  size_t kbase = (size_t)bh * (2048 * 64) + (size_t)ch * 4096;
  size_t gb = (size_t)bh * 2048 + ch * 64;
  size_t cb4096 = (size_t)(bh * 32 + ch) * 4096;

  // --- stage K as bf16, XOR-swizzled (chunk ^= row&7) to kill 128B-row conflicts
  {
    int row = tid >> 2, c16 = (tid & 3) * 16;
    const float* src = &khat[kbase + row * 64 + c16];
    float4 f0 = *(const float4*)(src + 0);
    float4 f1 = *(const float4*)(src + 4);
    float4 f2 = *(const float4*)(src + 8);
    float4 f3 = *(const float4*)(src + 12);
    bf16x8 h0, h1;
    h0[0] = (__bf16)f0.x; h0[1] = (__bf16)f0.y; h0[2] = (__bf16)f0.z; h0[3] = (__bf16)f0.w;
    h0[4] = (__bf16)f1.x; h0[5] = (__bf16)f1.y; h0[6] = (__bf16)f1.z; h0[7] = (__bf16)f1.w;
    h1[0] = (__bf16)f2.x; h1[1] = (__bf16)f2.y; h1[2] = (__bf16)f2.z; h1[3] = (__bf16)f2.w;
    h1[4] = (__bf16)f3.x; h1[5] = (__bf16)f3.y; h1[6] = (__bf16)f3.z; h1[7] = (__bf16)f3.w;
    int ch0 = ((c16 >> 3) + 0) ^ (row & 7);
    int ch1 = ((c16 >> 3) + 1) ^ (row & 7);
    *(bf16x8*)&Kbf[row * 64 + ch0 * 8] = h0;
    *(bf16x8*)&Kbf[row * 64 + ch1 * 8] = h1;
  }
  // --- zero Msh (so substitution can over-read float4 chunks safely)
  for (int i = tid; i < 64 * 68; i += 256) Msh[i] = 0.f;
  // --- g/beta load + wave-parallel inclusive scan (wave 0 only)
  if (tid < 64) {
    float g = gk_arr[gb + tid];
    float bv = beta_arr[gb + tid];
#pragma unroll
    for (int d = 1; d < 64; d <<= 1) {
      float n = __shfl_up(g, d, 64);
      if (tid >= d) g += n;
    }
    cumsh[tid] = g;
    bsh[tid] = bv;
    cumbuf[(size_t)(bh * 32 + ch) * 64 + tid] = g;
  }
  __syncthreads();

  // --- M = tril(K K^T) scaled, via MFMA. wave w owns rows 16w..16w+15.
  {
    f32x4 macc[4];
#pragma unroll
    for (int c = 0; c < 4; c++) macc[c] = (f32x4){0.f, 0.f, 0.f, 0.f};
    int arow = w * 16 + (lane & 15);
    int kb = lane >> 4;
    bf16x8 af0 = *(const bf16x8*)&Kbf[arow * 64 + ((0 + kb) ^ (arow & 7)) * 8];
    bf16x8 af1 = *(const bf16x8*)&Kbf[arow * 64 + ((4 + kb) ^ (arow & 7)) * 8];
#pragma unroll
    for (int c = 0; c < 4; c++) {
      if (c <= w) {
        int brow = c * 16 + (lane & 15);
        bf16x8 bf0 = *(const bf16x8*)&Kbf[brow * 64 + ((0 + kb) ^ (brow & 7)) * 8];
        bf16x8 bf1 = *(const bf16x8*)&Kbf[brow * 64 + ((4 + kb) ^ (brow & 7)) * 8];
        macc[c] = __builtin_amdgcn_mfma_f32_16x16x32_bf16(af0, bf0, macc[c], 0, 0, 0);
        macc[c] = __builtin_amdgcn_mfma_f32_16x16x32_bf16(af1, bf1, macc[c], 0, 0, 0);
      }
    }
    // scale + write lower tiles
    float bt[4], ct[4];
#pragma unroll
    for (int j = 0; j < 4; j++) {
      int trow = w * 16 + (lane >> 4) * 4 + j;
      bt[j] = bsh[trow];
      ct[j] = cumsh[trow];
    }
#pragma unroll
    for (int c = 0; c < 4; c++) {
      if (c <= w) {
        int scol = c * 16 + (lane & 15);
        float cums = cumsh[scol];
#pragma unroll
        for (int j = 0; j < 4; j++) {
          int trow = w * 16 + (lane >> 4) * 4 + j;
          float val = macc[c][j] * bt[j] * __expf(ct[j] - cums);
          Msh[trow * 68 + scol] = (scol < trow) ? val : 0.f;
        }
      }
    }
  }

  // --- RHS columns into registers (threads 0..127: c<64 -> U col, else W col)
  float uw[64];
  int c = tid;
  if (tid < 128) {
    bool isU = c < 64;
    int cc = c & 63;
    const float* src = isU ? &vhat[kbase + cc] : &khat[kbase + cc];
#pragma unroll
    for (int t = 0; t < 64; t++) {
      float r = src[t * 64] * bsh[t];
      if (!isU) r *= __expf(cumsh[t]);
      uw[t] = r;
    }
  }
  __syncthreads();   // Msh ready

  if (tid < 128) {
    // forward substitution, fully in registers; M row chunks broadcast
#pragma unroll
    for (int t = 1; t < 64; t++) {
      float acc = 0.f;
#pragma unroll
      for (int q = 0; q <= (t - 1) >> 2; q++) {
        float4 m4 = *(const float4*)&Msh[t * 68 + q * 4];
        acc += m4.x * uw[q * 4 + 0] + m4.y * uw[q * 4 + 1] +
               m4.z * uw[q * 4 + 2] + m4.w * uw[q * 4 + 3];
      }
      uw[t] -= acc;
    }
    bool isU = c < 64;
    int cc = c & 63;
    float* dst = isU ? &Ubuf[cb4096 + cc] : &Wbuf[cb4096 + cc];
#pragma unroll
    for (int t = 0; t < 64; t++) dst[t * 64] = uw[t];
  }
}

// ---------------------------------------------------------------------------
// Phase B v3 (sequential over chunks, software-pipelined): grid 256 = bh*8+vb.
// S in REGISTERS (2 cols/thread); chunk ch+1 operands (W row, K tile, U, cum)
// loaded while chunk ch computes; K double-buffered in LDS. Ping-pong register
// names via 2x-unrolled macro (no runtime-indexed reg arrays).
#define CHUNK_STEP(CH, WC, WN, UVC, UVN, CUMC, CUMN, CUR, NXT)                  \
  {                                                                             \
    size_t cb = cbb + (CH);                                                     \
    int chn = (CH) < 31 ? (CH) + 1 : 31;                                        \
    size_t cbn = cbb + chn;                                                     \
    /* issue next-chunk loads (independent of S) */                             \
    _Pragma("unroll")                                                           \
    for (int i4 = 0; i4 < 16; i4++) {                                           \
      float4 wv = *(const float4*)&Wbuf[cbn * 4096 + (size_t)lane * 64 + i4 * 4]; \
      WN[i4 * 4 + 0] = wv.x; WN[i4 * 4 + 1] = wv.y;                             \
      WN[i4 * 4 + 2] = wv.z; WN[i4 * 4 + 3] = wv.w;                             \
    }                                                                           \
    UVN = *(const float2*)&Ubuf[cbn * 4096 + (size_t)lane * 64 + c0];           \
    CUMN = cumbuf[cbn * 64 + lane];                                             \
    float4 knext[4];                                                            \
    _Pragma("unroll")                                                           \
    for (int n4 = 0; n4 < 4; n4++) {                                            \
      int n = tid + n4 * 256;                                                   \
      knext[n4] = *(const float4*)&khat[bhbase + (size_t)chn * 4096 + (size_t)n * 4]; \
    }                                                                           \
    /* compute current chunk */                                                 \
    float cum63 = rdlane(CUMC, 63);                                             \
    float sc = __expf(cum63 - CUMC);                                            \
    float Gend = __expf(cum63);                                                 \
    Sch[cb * 4096 + (size_t)(c0 + 0) * 64 + lane] = S0;                         \
    Sch[cb * 4096 + (size_t)(c0 + 1) * 64 + lane] = S1;                         \
    float a0 = 0.f, a1 = 0.f;                                                   \
    _Pragma("unroll")                                                           \
    for (int i = 0; i < 64; i++) {                                              \
      float s0 = rdlane(S0, i), s1 = rdlane(S1, i);                             \
      a0 += WC[i] * s0; a1 += WC[i] * s1;                                       \
    }                                                                           \
    float D0 = sc * (UVC.x - a0), D1 = sc * (UVC.y - a1);                       \
    float n0 = 0.f, n1 = 0.f;                                                   \
    _Pragma("unroll")                                                           \
    for (int t = 0; t < 64; t++) {                                              \
      float d0 = rdlane(D0, t), d1 = rdlane(D1, t);                             \
      float kk = Ksh[CUR][t * 68 + lane];                                       \
      n0 += kk * d0; n1 += kk * d1;                                             \
    }                                                                           \
    S0 = Gend * S0 + n0; S1 = Gend * S1 + n1;                                   \
    /* write next K buffer, one barrier per chunk */                            \
    _Pragma("unroll")                                                           \
    for (int n4 = 0; n4 < 4; n4++) {                                            \
      int n = tid + n4 * 256;                                                   \
      int row = n >> 4, col = (n & 15) * 4;                                     \
      *(float4*)&Ksh[NXT][row * 68 + col] = knext[n4];                          \
    }                                                                           \
    __syncthreads();                                                            \
  }

__global__ __launch_bounds__(256) void k_chunkB(
    const float* __restrict__ khat, const float* __restrict__ cumbuf,
    const float* __restrict__ Ubuf, const float* __restrict__ Wbuf,
    float* __restrict__ Sch) {
  int bid = blockIdx.x;
  int bh = bid >> 3, vb = bid & 7;
  int tid = threadIdx.x;
  int lane = tid & 63, q_ = tid >> 6;
  int c0 = vb * 8 + q_ * 2;
  __shared__ float Ksh[2][64 * 68];
  size_t bhbase = (size_t)bh * (2048 * 64);
  size_t cbb = (size_t)bh * 32;

  // prologue: chunk 0 operands
  float Wa[64], Wb[64];
  float2 uva, uvb;
  float cuma, cumb;
#pragma unroll
  for (int i4 = 0; i4 < 16; i4++) {
    float4 wv = *(const float4*)&Wbuf[cbb * 4096 + (size_t)lane * 64 + i4 * 4];
    Wa[i4 * 4 + 0] = wv.x; Wa[i4 * 4 + 1] = wv.y;
    Wa[i4 * 4 + 2] = wv.z; Wa[i4 * 4 + 3] = wv.w;
  }
  uva = *(const float2*)&Ubuf[cbb * 4096 + (size_t)lane * 64 + c0];
  cuma = cumbuf[cbb * 64 + lane];
  {
    float4 k0[4];
#pragma unroll
    for (int n4 = 0; n4 < 4; n4++) {
      int n = tid + n4 * 256;
      k0[n4] = *(const float4*)&khat[bhbase + (size_t)n * 4];
    }
#pragma unroll
    for (int n4 = 0; n4 < 4; n4++) {
      int n = tid + n4 * 256;
      int row = n >> 4, col = (n & 15) * 4;
      *(float4*)&Ksh[0][row * 68 + col] = k0[n4];
    }
  }
  __syncthreads();
  float S0 = 0.f, S1 = 0.f;
  for (int ch = 0; ch < 32; ch += 2) {
    CHUNK_STEP(ch, Wa, Wb, uva, uvb, cuma, cumb, 0, 1);
    CHUNK_STEP(ch + 1, Wb, Wa, uvb, uva, cumb, cuma, 1, 0);
  }
}
#undef CHUNK_STEP

// Phase C (parallel, 1024 blocks): O = diag(G) Q S_in + (QK^T . decaymask) Delta
__global__ __launch_bounds__(256) void k_out(
    const float* __restrict__ qhat, const float* __restrict__ khat,
    const float* __restrict__ cumbuf, const float* __restrict__ Ubuf,
    const float* __restrict__ Wbuf, const float* __restrict__ Sch,
    float* __restrict__ o_pre) {
  int bid = blockIdx.x;
  int bh = bid >> 5, ch = bid & 31;
  int b = bh >> 4, h = bh & 15;
  int tid = threadIdx.x;
  __shared__ float B1[64][65];  // W -> Q -> P
  __shared__ float B2[64][65];  // S -> K
  __shared__ float B3[64][65];  // Delta
  __shared__ float cumsh[64];
  size_t cb = (size_t)(bh * 32 + ch);
  size_t kbase = (size_t)bh * (2048 * 64) + (size_t)ch * 4096;
  if (tid < 64) cumsh[tid] = cumbuf[cb * 64 + tid];
  for (int idx = tid; idx < 4096; idx += 256) {
    B1[idx >> 6][idx & 63] = Wbuf[cb * 4096 + idx];
    B2[idx & 63][idx >> 6] = Sch[cb * 4096 + idx];   // Sch is column-major
  }
  __syncthreads();
  int t_ = tid & 63, q_ = tid >> 6;   // q_ 0..3 -> 16 cols each
  int c0 = q_ * 16;
  float acc[16], o1[16], p[16];
  // Delta = U - W S  -> B3
#pragma unroll
  for (int j = 0; j < 16; j++) acc[j] = 0.f;
  for (int i = 0; i < 64; i++) {
    float w = B1[t_][i];
#pragma unroll
    for (int j = 0; j < 16; j++) acc[j] += w * B2[i][c0 + j];
  }
#pragma unroll
  for (int j = 0; j < 16; j += 4) {
    float4 u = *(const float4*)&Ubuf[cb * 4096 + (size_t)t_ * 64 + c0 + j];
    B3[t_][c0 + j + 0] = u.x - acc[j + 0];
    B3[t_][c0 + j + 1] = u.y - acc[j + 1];
    B3[t_][c0 + j + 2] = u.z - acc[j + 2];
    B3[t_][c0 + j + 3] = u.w - acc[j + 3];
  }
  __syncthreads();
  // B1 <- Q
  for (int idx = tid; idx < 4096; idx += 256)
    B1[idx >> 6][idx & 63] = qhat[kbase + idx];
  __syncthreads();
  // O1 = Gt * (Q S)
#pragma unroll
  for (int j = 0; j < 16; j++) o1[j] = 0.f;
  for (int i = 0; i < 64; i++) {
    float qv = B1[t_][i];
#pragma unroll
    for (int j = 0; j < 16; j++) o1[j] += qv * B2[i][c0 + j];
  }
  {
    float Gt = __expf(cumsh[t_]);
#pragma unroll
    for (int j = 0; j < 16; j++) o1[j] *= Gt;
  }
  __syncthreads();
  // B2 <- K
  for (int idx = tid; idx < 4096; idx += 256)
    B2[idx >> 6][idx & 63] = khat[kbase + idx];
  __syncthreads();
  // P[t][s] = (q_t.k_s) exp(cum_t-cum_s), s<=t
#pragma unroll
  for (int m = 0; m < 16; m++) {
    int s = c0 + m;
    float d = 0.f;
    if (s <= t_) {
      for (int i = 0; i < 64; i++) d += B1[t_][i] * B2[s][i];
      d *= __expf(cumsh[t_] - cumsh[s]);
    }
    p[m] = d;
  }
  __syncthreads();
#pragma unroll
  for (int m = 0; m < 16; m++) B1[t_][c0 + m] = p[m];
  __syncthreads();
  // O = O1 + P Delta
  for (int s = 0; s < 64; s++) {
    float pv = B1[t_][s];
#pragma unroll
    for (int j = 0; j < 16; j++) o1[j] += pv * B3[s][c0 + j];
  }
  size_t ob = ((size_t)(b * 2048 + ch * 64 + t_)) * 1024 + h * 64 + c0;
#pragma unroll
  for (int j = 0; j < 16; j += 4) {
    float4 o4 = {o1[j], o1[j + 1], o1[j + 2], o1[j + 3]};
    *(float4*)&o_pre[ob + j] = o4;
  }
}

// ---------------------------------------------------------------------------
// epilogue: per-(m,h) RMSNorm(64, eps 1e-5, mean) * gnorm_w * silu(g) -> bf16
__global__ __launch_bounds__(256) void k_gatenorm(const float* __restrict__ o_pre,
    const float* __restrict__ g, const float* __restrict__ gnw,
    __bf16* __restrict__ obf) {
  int m = blockIdx.x;
  int tid = threadIdx.x;
  size_t baseo = (size_t)m * 1024 + tid * 4;
  float4 ov = *(const float4*)&o_pre[baseo];
  float ss = ov.x * ov.x + ov.y * ov.y + ov.z * ov.z + ov.w * ov.w;
  ss += __shfl_xor(ss, 1);
  ss += __shfl_xor(ss, 2);
  ss += __shfl_xor(ss, 4);
  ss += __shfl_xor(ss, 8);
  float inv = rsqrtf(ss * (1.f / 64.f) + 1e-5f);
  float4 gv = *(const float4*)&g[baseo];
  int d0 = (tid & 15) * 4;
  float r0 = ov.x * inv * gnw[d0 + 0] * (gv.x * (1.f / (1.f + __expf(-gv.x))));
  float r1 = ov.y * inv * gnw[d0 + 1] * (gv.y * (1.f / (1.f + __expf(-gv.y))));
  float r2 = ov.z * inv * gnw[d0 + 2] * (gv.z * (1.f / (1.f + __expf(-gv.z))));
  float r3 = ov.w * inv * gnw[d0 + 3] * (gv.w * (1.f / (1.f + __expf(-gv.w))));
  bf16x4 o;
  o.x = (__bf16)r0; o.y = (__bf16)r1; o.z = (__bf16)r2; o.w = (__bf16)r3;
  *(bf16x4*)&obf[baseo] = o;
}

// ---------------------------------------------------------------------------
extern "C" void kernel_launch(void* const* d_in, const int* in_sizes, int n_in,
                              void* d_out, int out_size, void* d_ws, size_t ws_size,
                              hipStream_t stream) {
  const float* x = (const float*)d_in[0];
  const float* Wq = (const float*)d_in[1];
  const float* Wk = (const float*)d_in[2];
  const float* Wv = (const float*)d_in[3];
  const float* Wo = (const float*)d_in[4];
  const float* Wg = (const float*)d_in[5];
  const float* Wgk = (const float*)d_in[6];
  const float* Wb = (const float*)d_in[7];
  const float* bb = (const float*)d_in[8];
  const float* A_log = (const float*)d_in[9];
  const float* cqw = (const float*)d_in[10];
  const float* ckw = (const float*)d_in[11];
  const float* cvw = (const float*)d_in[12];
  const float* gnw = (const float*)d_in[13];
  const float* dtb = (const float*)d_in[14];
  float* out = (float*)d_out;

  char* ws = (char*)d_ws;
  __bf16* xbf   = (__bf16*)(ws + 0);            // 8 MB  (later obf)
  __bf16* wq_t  = (__bf16*)(ws + 8388608);      // 2 MB  (later cumbuf)
  __bf16* wk_t  = (__bf16*)(ws + 10485760);
  __bf16* wv_t  = (__bf16*)(ws + 12582912);
  __bf16* wg_t  = (__bf16*)(ws + 14680064);
  __bf16* wo_t  = (__bf16*)(ws + 16777216);
  float* qpre   = (float*)(ws + 18874368);      // 16 MB (later o_pre)
  float* kpre   = (float*)(ws + 35651584);      // 16 MB (later Ubuf)
  float* vpre   = (float*)(ws + 52428800);      // 16 MB (later Wbuf)
  float* gbuf   = (float*)(ws + 69206016);
  float* qhat   = (float*)(ws + 85983232);
  float* khat   = (float*)(ws + 102760448);
  float* vhat   = (float*)(ws + 119537664);     // 16 MB (later Sch)
  float* gk_arr = (float*)(ws + 136314880);     // 256 KB
  float* beta_a = (float*)(ws + 136577024);     // 256 KB
  float* o_pre  = qpre;
  __bf16* obf   = xbf;
  float* cumbuf = (float*)wq_t;   // 256 KB, wq_t dead after big gemm
  float* Ubuf   = kpre;           // kpre dead after conv
  float* Wbuf   = vpre;           // vpre dead after conv
  float* Sch    = vhat;           // vhat dead after chunkA
  // gk/beta projection staging — both live only between gemm and conv:
  __bf16* wgb_t = (__bf16*)khat;  // 256 KB in khat region (conv writes after)
  float* pbuf   = qhat;           // 2 MB in qhat region   (conv writes after)

  k_convert<<<dim3((NM * NC / 4 + 255) / 256), 256, 0, stream>>>(x, xbf, NM * NC / 4);
  dim3 tg(16, 16);
  k_transpose<<<tg, 256, 0, stream>>>(Wq, wq_t);
  k_transpose<<<tg, 256, 0, stream>>>(Wk, wk_t);
  k_transpose<<<tg, 256, 0, stream>>>(Wv, wv_t);
  k_transpose<<<tg, 256, 0, stream>>>(Wg, wg_t);
  k_transpose<<<tg, 256, 0, stream>>>(Wo, wo_t);
  k_buildwgb<<<16, 256, 0, stream>>>(Wgk, Wb, wgb_t);
  // fused q/k/v/g + gk/beta projections (grid.y = 4*8 + 1)
  k_gemm<<<dim3(NM / 128, 33), 256, 0, stream>>>(xbf, wq_t, wk_t, wv_t, wg_t, wgb_t,
                                                 qpre, kpre, vpre, gbuf, pbuf, 8);
  k_projpost<<<NM * 32 / 256, 256, 0, stream>>>(pbuf, bb, A_log, dtb, gk_arr, beta_a);
  k_conv<<<dim3(NT / 64, NB * NH, 3), 256, 0, stream>>>(qpre, kpre, vpre, cqw, ckw,
                                                        cvw, qhat, khat, vhat);
  // chunked gated-delta scan
  k_chunkA<<<1024, 256, 0, stream>>>(khat, vhat, gk_arr, beta_a, cumbuf, Ubuf, Wbuf);
  k_chunkB<<<256, 256, 0, stream>>>(khat, cumbuf, Ubuf, Wbuf, Sch);
  k_out<<<1024, 256, 0, stream>>>(qhat, khat, cumbuf, Ubuf, Wbuf, Sch, o_pre);
  k_gatenorm<<<NM, 256, 0, stream>>>(o_pre, gbuf, gnw, obf);
  k_gemm<<<dim3(NM / 128, 8), 256, 0, stream>>>(obf, wo_t, nullptr, nullptr, nullptr,
                                                nullptr, out, nullptr, nullptr, nullptr,
                                                nullptr, 8);
}